// Round 1
// baseline (1963.704 us; speedup 1.0000x reference)
//
#include <hip/hip_runtime.h>

#define NN 50000
#define DIN 256
#define HD 64
#define NHEAD 4

static inline int cdiv(long a, long b) { return (int)((a + b - 1) / b); }

// ---------------- elementwise helpers ----------------
__global__ __launch_bounds__(256) void k_fill(float* __restrict__ p, float v, int n) {
  int i = blockIdx.x * 256 + threadIdx.x;
  if (i < n) p[i] = v;
}

__global__ __launch_bounds__(256) void k_degcount(const int* __restrict__ dst,
                                                  float* __restrict__ deg, int E) {
  int i = blockIdx.x * 256 + threadIdx.x;
  if (i < E) atomicAdd(&deg[dst[i]], 1.0f);
}

__global__ __launch_bounds__(256) void k_rsqrt(float* __restrict__ d, int n) {
  int i = blockIdx.x * 256 + threadIdx.x;
  if (i < n) d[i] = 1.0f / sqrtf(d[i]);   // deg >= 1 always (self loops)
}

// out[i] = (resid ? resid[i] : 0) + relu(agg[i] + bias[i&63])
__global__ __launch_bounds__(256) void k_post(const float* __restrict__ agg,
                                              const float* __restrict__ bias,
                                              const float* __restrict__ resid,
                                              float* __restrict__ out, int total) {
  int i = blockIdx.x * 256 + threadIdx.x;
  if (i >= total) return;
  float v = agg[i] + bias[i & (HD - 1)];
  v = v > 0.f ? v : 0.f;
  if (resid) v += resid[i];
  out[i] = v;
}

// ---------------- generic small-GEMM: C[n,KOUT] = A[n,KIN] @ W[KIN,KOUT] ----------------
// MODE 0: plain, 1: bias+relu, 2: bias
template <int KIN, int KOUT, int MODE, int LITER>
__global__ __launch_bounds__(256) void k_gemm(const float* __restrict__ A,
                                              const float* __restrict__ W,
                                              const float* __restrict__ bias,
                                              float* __restrict__ C, int n) {
  __shared__ float Wl[KIN * KOUT];
  for (int i = threadIdx.x; i < KIN * KOUT; i += 256) Wl[i] = W[i];
  __syncthreads();
  constexpr int RPI = 256 / KOUT;  // rows per iteration
  int col = threadIdx.x & (KOUT - 1);
  int rloc = threadIdx.x / KOUT;
  int base = blockIdx.x * (RPI * LITER);
  for (int it = 0; it < LITER; ++it) {
    int row = base + it * RPI + rloc;
    if (row >= n) break;
    const float* a = A + (size_t)row * KIN;
    float acc = 0.f;
#pragma unroll 16
    for (int k = 0; k < KIN; ++k) acc = fmaf(a[k], Wl[k * KOUT + col], acc);
    float r = acc;
    if (MODE != 0) {
      r = acc + bias[col];
      if (MODE == 1) r = r > 0.f ? r : 0.f;
    }
    C[(size_t)row * KOUT + col] = r;
  }
}

// ---------------- GCN edge aggregation: out[dst] += P[src] * dinv[src]*dinv[dst] ----------------
__global__ __launch_bounds__(256) void k_agg(const float* __restrict__ P,
                                             const int* __restrict__ src,
                                             const int* __restrict__ dst,
                                             const float* __restrict__ dinv,
                                             float* __restrict__ out, int E, int nE) {
  int gid = blockIdx.x * 256 + threadIdx.x;
  int e = gid >> 6, lane = gid & 63;
  if (e >= nE) return;
  int s, d;
  if (e < E) { s = src[e]; d = dst[e]; } else { s = d = e - E; }
  float nrm = dinv[s] * dinv[d];
  float v = P[(size_t)s * HD + lane] * nrm;
  atomicAdd(out + (size_t)d * HD + lane, v);
}

// ---------------- GAT ----------------
// a_s[n,h] = dot(xg[n,h,:], att_src[h,:]); a_d likewise
__global__ __launch_bounds__(256) void k_att(const float* __restrict__ xg,
                                             const float* __restrict__ att_src,
                                             const float* __restrict__ att_dst,
                                             float* __restrict__ a_s,
                                             float* __restrict__ a_d, int n) {
  int idx = blockIdx.x * 256 + threadIdx.x;
  if (idx >= n * NHEAD) return;
  int nd = idx >> 2, h = idx & 3;
  const float* v = xg + (size_t)nd * (NHEAD * HD) + h * HD;
  const float* as = att_src + h * HD;
  const float* ad = att_dst + h * HD;
  float s1 = 0.f, s2 = 0.f;
#pragma unroll 16
  for (int f = 0; f < HD; ++f) {
    s1 = fmaf(v[f], as[f], s1);
    s2 = fmaf(v[f], ad[f], s2);
  }
  a_s[idx] = s1;
  a_d[idx] = s2;
}

__device__ __forceinline__ unsigned enc_f32(float v) {
  unsigned b = __float_as_uint(v);
  return (b & 0x80000000u) ? ~b : (b | 0x80000000u);
}
__device__ __forceinline__ float dec_f32(unsigned u) {
  return (u & 0x80000000u) ? __uint_as_float(u & 0x7FFFFFFFu) : __uint_as_float(~u);
}

__device__ __forceinline__ float leaky(float v) { return v > 0.f ? v : 0.2f * v; }

__global__ __launch_bounds__(256) void k_gat_max(const int* __restrict__ src,
                                                 const int* __restrict__ dst,
                                                 const float* __restrict__ a_s,
                                                 const float* __restrict__ a_d,
                                                 unsigned* __restrict__ menc, int E, int nE) {
  int idx = blockIdx.x * 256 + threadIdx.x;
  if (idx >= nE * NHEAD) return;
  int e = idx >> 2, h = idx & 3;
  int s, d;
  if (e < E) { s = src[e]; d = dst[e]; } else { s = d = e - E; }
  float v = leaky(a_s[s * NHEAD + h] + a_d[d * NHEAD + h]);
  atomicMax(&menc[d * NHEAD + h], enc_f32(v));
}

__global__ __launch_bounds__(256) void k_gat_exp(const int* __restrict__ src,
                                                 const int* __restrict__ dst,
                                                 const float* __restrict__ a_s,
                                                 const float* __restrict__ a_d,
                                                 const unsigned* __restrict__ menc,
                                                 float* __restrict__ ssum,
                                                 float* __restrict__ exb, int E, int nE) {
  int idx = blockIdx.x * 256 + threadIdx.x;
  if (idx >= nE * NHEAD) return;
  int e = idx >> 2, h = idx & 3;
  int s, d;
  if (e < E) { s = src[e]; d = dst[e]; } else { s = d = e - E; }
  float v = leaky(a_s[s * NHEAD + h] + a_d[d * NHEAD + h]);
  float m = dec_f32(menc[d * NHEAD + h]);
  float ex = expf(v - m);
  exb[idx] = ex;
  atomicAdd(&ssum[d * NHEAD + h], ex);
}

// hg_full[dst, h, :] += xg[src, h, :] * alpha[e,h]
__global__ __launch_bounds__(256) void k_gat_scatter(const float* __restrict__ xg,
                                                     const int* __restrict__ src,
                                                     const int* __restrict__ dst,
                                                     const float* __restrict__ exb,
                                                     const float* __restrict__ ssum,
                                                     float* __restrict__ hgf, int E, int nE) {
  int gid = blockIdx.x * 256 + threadIdx.x;
  int e = gid >> 6, lane = gid & 63;
  if (e >= nE) return;
  int s, d;
  if (e < E) { s = src[e]; d = dst[e]; } else { s = d = e - E; }
  const float* xs = xg + (size_t)s * (NHEAD * HD);
  float* hd = hgf + (size_t)d * (NHEAD * HD);
#pragma unroll
  for (int h = 0; h < NHEAD; ++h) {
    float alpha = exb[e * NHEAD + h] / ssum[d * NHEAD + h];
    atomicAdd(hd + h * HD + lane, xs[h * HD + lane] * alpha);
  }
}

// hg[n,f] = mean_h(hg_full) + bg[f]; also gsum[f] += hg[n,f]
__global__ __launch_bounds__(256) void k_hg_final(const float* __restrict__ hgf,
                                                  const float* __restrict__ bg,
                                                  float* __restrict__ hg,
                                                  float* __restrict__ gsum, int n) {
  __shared__ float red[256];
  int f = threadIdx.x & 63, g = threadIdx.x >> 6;
  float local = 0.f;
  for (int nd = blockIdx.x * 4 + g; nd < n; nd += gridDim.x * 4) {
    const float* hf = hgf + (size_t)nd * (NHEAD * HD);
    float v = 0.25f * (hf[f] + hf[64 + f] + hf[128 + f] + hf[192 + f]) + bg[f];
    hg[(size_t)nd * HD + f] = v;
    local += v;
  }
  red[threadIdx.x] = local;
  __syncthreads();
  if (threadIdx.x < 64)
    atomicAdd(&gsum[f], red[f] + red[64 + f] + red[128 + f] + red[192 + f]);
}

// tiny classifier head: out[0:2]
__global__ __launch_bounds__(64) void k_cls(const float* __restrict__ gsum,
                                            const float* __restrict__ Wc1,
                                            const float* __restrict__ bc1,
                                            const float* __restrict__ Wc2,
                                            const float* __restrict__ bc2,
                                            float* __restrict__ out, int n) {
  __shared__ float hgl[64];
  __shared__ float t1[32];
  int t = threadIdx.x;
  hgl[t] = gsum[t] / (float)n;
  __syncthreads();
  if (t < 32) {
    float a = bc1[t];
#pragma unroll 16
    for (int f = 0; f < 64; ++f) a = fmaf(hgl[f], Wc1[f * 32 + t], a);
    t1[t] = a > 0.f ? a : 0.f;
  }
  __syncthreads();
  if (t < 2) {
    float a = bc2[t];
#pragma unroll
    for (int j = 0; j < 32; ++j) a = fmaf(t1[j], Wc2[j * 2 + t], a);
    out[t] = a;
  }
}

extern "C" void kernel_launch(void* const* d_in, const int* in_sizes, int n_in,
                              void* d_out, int out_size, void* d_ws, size_t ws_size,
                              hipStream_t stream) {
  const float* x = (const float*)d_in[0];
  const int* ei = (const int*)d_in[1];
  const float* W0 = (const float*)d_in[2];
  const float* b0 = (const float*)d_in[3];
  const float* W1 = (const float*)d_in[4];
  const float* b1 = (const float*)d_in[5];
  const float* W2 = (const float*)d_in[6];
  const float* b2 = (const float*)d_in[7];
  const float* Wg = (const float*)d_in[8];
  const float* att_src = (const float*)d_in[9];
  const float* att_dst = (const float*)d_in[10];
  const float* bg = (const float*)d_in[11];
  const float* Wc1 = (const float*)d_in[12];
  const float* bc1 = (const float*)d_in[13];
  const float* Wc2 = (const float*)d_in[14];
  const float* bc2 = (const float*)d_in[15];
  const float* Wr1 = (const float*)d_in[16];
  const float* br1 = (const float*)d_in[17];
  const float* Wr2 = (const float*)d_in[18];
  const float* br2 = (const float*)d_in[19];

  const int n = in_sizes[0] / DIN;          // 50000
  const int E = in_sizes[1] / 2;            // 800000
  const int nE = E + n;
  const int* src = ei;
  const int* dst = ei + E;

  // ---- workspace layout (floats), 256B-ish aligned ----
  float* ws = (float*)d_ws;
  size_t off = 0;
  auto alloc = [&](size_t nfloats) {
    float* p = ws + off;
    off += (nfloats + 63) & ~(size_t)63;
    return p;
  };
  float* DINV = alloc(n);                 // deg -> dinv in place
  float* P = alloc((size_t)n * 256);      // GEMM outputs / xg / r1
  float* AGG = alloc((size_t)n * 256);    // GCN agg (n*64) / hg_full (n*256)
  float* Hb = alloc((size_t)n * HD);      // hidden h
  float* ASD = alloc((size_t)n * NHEAD);  // a_src
  float* ADD = alloc((size_t)n * NHEAD);  // a_dst
  float* MEB = alloc((size_t)n * NHEAD);  // encoded max (as unsigned)
  float* SSUM = alloc((size_t)n * NHEAD);
  float* EXB = alloc((size_t)nE * NHEAD);
  float* GSUM = alloc(64);
  (void)ws_size;

  float* out = (float*)d_out;
  float* out_cls = out;                   // 2
  float* out_rec = out + 2;               // n*256
  float* out_hg = out + 2 + (size_t)n * 256;  // n*64

  const int TB = 256;
  // ---- degrees & norm ----
  k_fill<<<cdiv(n, TB), TB, 0, stream>>>(DINV, 1.0f, n);
  k_degcount<<<cdiv(E, TB), TB, 0, stream>>>(dst, DINV, E);
  k_rsqrt<<<cdiv(n, TB), TB, 0, stream>>>(DINV, n);

  // ---- GCN layer 0 ----
  k_gemm<256, 64, 0, 4><<<cdiv(n, 16), TB, 0, stream>>>(x, W0, nullptr, P, n);
  k_fill<<<cdiv((long)n * HD, TB), TB, 0, stream>>>(AGG, 0.f, n * HD);
  k_agg<<<cdiv((long)nE * 64, TB), TB, 0, stream>>>(P, src, dst, DINV, AGG, E, nE);
  k_post<<<cdiv((long)n * HD, TB), TB, 0, stream>>>(AGG, b0, nullptr, Hb, n * HD);

  // ---- GCN layer 1 (residual) ----
  k_gemm<64, 64, 0, 4><<<cdiv(n, 16), TB, 0, stream>>>(Hb, W1, nullptr, P, n);
  k_fill<<<cdiv((long)n * HD, TB), TB, 0, stream>>>(AGG, 0.f, n * HD);
  k_agg<<<cdiv((long)nE * 64, TB), TB, 0, stream>>>(P, src, dst, DINV, AGG, E, nE);
  k_post<<<cdiv((long)n * HD, TB), TB, 0, stream>>>(AGG, b1, Hb, Hb, n * HD);

  // ---- GCN layer 2 (residual) ----
  k_gemm<64, 64, 0, 4><<<cdiv(n, 16), TB, 0, stream>>>(Hb, W2, nullptr, P, n);
  k_fill<<<cdiv((long)n * HD, TB), TB, 0, stream>>>(AGG, 0.f, n * HD);
  k_agg<<<cdiv((long)nE * 64, TB), TB, 0, stream>>>(P, src, dst, DINV, AGG, E, nE);
  k_post<<<cdiv((long)n * HD, TB), TB, 0, stream>>>(AGG, b2, Hb, Hb, n * HD);

  // ---- GAT ----
  k_gemm<64, 256, 0, 16><<<cdiv(n, 16), TB, 0, stream>>>(Hb, Wg, nullptr, P, n);  // xg
  k_att<<<cdiv((long)n * NHEAD, TB), TB, 0, stream>>>(P, att_src, att_dst, ASD, ADD, n);
  k_fill<<<cdiv((long)n * NHEAD, TB), TB, 0, stream>>>(MEB, 0.f, n * NHEAD);  // bits 0 < any enc
  k_gat_max<<<cdiv((long)nE * NHEAD, TB), TB, 0, stream>>>(src, dst, ASD, ADD,
                                                           (unsigned*)MEB, E, nE);
  k_fill<<<cdiv((long)n * NHEAD, TB), TB, 0, stream>>>(SSUM, 0.f, n * NHEAD);
  k_gat_exp<<<cdiv((long)nE * NHEAD, TB), TB, 0, stream>>>(src, dst, ASD, ADD,
                                                           (const unsigned*)MEB, SSUM, EXB, E, nE);
  k_fill<<<cdiv((long)n * 256, TB), TB, 0, stream>>>(AGG, 0.f, n * 256);
  k_gat_scatter<<<cdiv((long)nE * 64, TB), TB, 0, stream>>>(P, src, dst, EXB, SSUM, AGG, E, nE);
  k_fill<<<1, TB, 0, stream>>>(GSUM, 0.f, 64);
  k_hg_final<<<512, TB, 0, stream>>>(AGG, bg, out_hg, GSUM, n);

  // ---- heads ----
  k_cls<<<1, 64, 0, stream>>>(GSUM, Wc1, bc1, Wc2, bc2, out_cls, n);
  k_gemm<64, 64, 1, 4><<<cdiv(n, 16), TB, 0, stream>>>(out_hg, Wr1, br1, P, n);     // r1
  k_gemm<64, 256, 2, 16><<<cdiv(n, 16), TB, 0, stream>>>(P, Wr2, br2, out_rec, n);  // rec
}

// Round 2
// 1050.753 us; speedup vs baseline: 1.8689x; 1.8689x over previous
//
#include <hip/hip_runtime.h>

#define DIN 256
#define HD 64
#define NHEAD 4

static inline int cdiv(long a, long b) { return (int)((a + b - 1) / b); }

// ---------------- fills ----------------
__global__ __launch_bounds__(256) void k_fill(float* __restrict__ p, float v, int n) {
  int i = blockIdx.x * 256 + threadIdx.x;
  if (i < n) p[i] = v;
}
__global__ __launch_bounds__(256) void k_filli(int* __restrict__ p, int v, int n) {
  int i = blockIdx.x * 256 + threadIdx.x;
  if (i < n) p[i] = v;
}
__global__ __launch_bounds__(256) void k_copyi(const int* __restrict__ a, int* __restrict__ b, int n) {
  int i = blockIdx.x * 256 + threadIdx.x;
  if (i < n) b[i] = a[i];
}

// ---------------- CSR build ----------------
__global__ __launch_bounds__(256) void k_count(const int* __restrict__ dst,
                                               int* __restrict__ cnt, int E) {
  int i = blockIdx.x * 256 + threadIdx.x;
  if (i < E) atomicAdd(&cnt[dst[i]], 1);
}

__global__ __launch_bounds__(256) void k_bsum(const int* __restrict__ cnt,
                                              int* __restrict__ bsum, int n) {
  __shared__ int sd[256];
  int i = blockIdx.x * 256 + threadIdx.x;
  sd[threadIdx.x] = (i < n) ? cnt[i] : 0;
  __syncthreads();
  for (int o = 128; o > 0; o >>= 1) {
    if (threadIdx.x < o) sd[threadIdx.x] += sd[threadIdx.x + o];
    __syncthreads();
  }
  if (threadIdx.x == 0) bsum[blockIdx.x] = sd[0];
}

__global__ __launch_bounds__(256) void k_bscan(const int* __restrict__ bsum,
                                               int* __restrict__ boff, int B) {
  __shared__ int sd[256];
  int t = threadIdx.x;
  int v = (t < B) ? bsum[t] : 0;
  sd[t] = v;
  __syncthreads();
  for (int o = 1; o < 256; o <<= 1) {
    int x = (t >= o) ? sd[t - o] : 0;
    __syncthreads();
    sd[t] += x;
    __syncthreads();
  }
  if (t < B) boff[t] = sd[t] - v;  // exclusive
}

__global__ __launch_bounds__(256) void k_rowptr(const int* __restrict__ cnt,
                                                const int* __restrict__ boff,
                                                int* __restrict__ row_ptr, int n, int total) {
  __shared__ int sd[256];
  int t = threadIdx.x;
  int i = blockIdx.x * 256 + t;
  int v = (i < n) ? cnt[i] : 0;
  sd[t] = v;
  __syncthreads();
  for (int o = 1; o < 256; o <<= 1) {
    int x = (t >= o) ? sd[t - o] : 0;
    __syncthreads();
    sd[t] += x;
    __syncthreads();
  }
  if (i < n) row_ptr[i] = boff[blockIdx.x] + sd[t] - v;
  if (i == n - 1) row_ptr[n] = total;
}

__global__ __launch_bounds__(256) void k_csrfill(const int* __restrict__ src,
                                                 const int* __restrict__ dst,
                                                 int* __restrict__ cursor,
                                                 int* __restrict__ csr_src, int E, int n) {
  int e = blockIdx.x * 256 + threadIdx.x;
  if (e < E) {
    int pos = atomicAdd(&cursor[dst[e]], 1);
    csr_src[pos] = src[e];
  } else if (e < E + n) {
    int i = e - E;
    int pos = atomicAdd(&cursor[i], 1);
    csr_src[pos] = i;
  }
}

__global__ __launch_bounds__(256) void k_dinv(const int* __restrict__ row_ptr,
                                              float* __restrict__ dinv, int n) {
  int i = blockIdx.x * 256 + threadIdx.x;
  if (i < n) dinv[i] = rsqrtf((float)(row_ptr[i + 1] - row_ptr[i]));
}

// ---------------- generic small-GEMM: C[n,KOUT] = A[n,KIN] @ W[KIN,KOUT] ----------------
// MODE 0: plain, 1: bias+relu, 2: bias
template <int KIN, int KOUT, int MODE, int LITER>
__global__ __launch_bounds__(256) void k_gemm(const float* __restrict__ A,
                                              const float* __restrict__ W,
                                              const float* __restrict__ bias,
                                              float* __restrict__ C, int n) {
  __shared__ float Wl[KIN * KOUT];
  for (int i = threadIdx.x; i < KIN * KOUT; i += 256) Wl[i] = W[i];
  __syncthreads();
  constexpr int RPI = 256 / KOUT;  // rows per iteration
  int col = threadIdx.x & (KOUT - 1);
  int rloc = threadIdx.x / KOUT;
  int base = blockIdx.x * (RPI * LITER);
  for (int it = 0; it < LITER; ++it) {
    int row = base + it * RPI + rloc;
    if (row >= n) break;
    const float* a = A + (size_t)row * KIN;
    float acc = 0.f;
#pragma unroll 16
    for (int k = 0; k < KIN; ++k) acc = fmaf(a[k], Wl[k * KOUT + col], acc);
    float r = acc;
    if (MODE != 0) {
      r = acc + bias[col];
      if (MODE == 1) r = r > 0.f ? r : 0.f;
    }
    C[(size_t)row * KOUT + col] = r;
  }
}

// ---------------- GCN aggregation, CSR gather, fused bias+relu+residual ----------------
// out[node,f] = (resid?resid:0) + relu( dinv[node]*sum_{s in nbrs} P[s,f]*dinv[s] + bias[f] )
__global__ __launch_bounds__(256) void k_agg_csr(const float* __restrict__ P,
                                                 const int* __restrict__ csr_src,
                                                 const int* __restrict__ row_ptr,
                                                 const float* __restrict__ dinv,
                                                 const float* __restrict__ bias,
                                                 const float* __restrict__ resid,
                                                 float* __restrict__ out, int n) {
  int node = (blockIdx.x * 256 + threadIdx.x) >> 6;
  int lane = threadIdx.x & 63;
  if (node >= n) return;
  int beg = row_ptr[node], end = row_ptr[node + 1];
  float acc = 0.f;
  for (int i = beg; i < end; ++i) {
    int s = csr_src[i];  // wave-uniform broadcast
    acc = fmaf(P[(size_t)s * HD + lane], dinv[s], acc);
  }
  float v = acc * dinv[node] + bias[lane];
  v = v > 0.f ? v : 0.f;
  if (resid) v += resid[(size_t)node * HD + lane];
  out[(size_t)node * HD + lane] = v;
}

// ---------------- GAT ----------------
__global__ __launch_bounds__(256) void k_att(const float* __restrict__ xg,
                                             const float* __restrict__ att_src,
                                             const float* __restrict__ att_dst,
                                             float* __restrict__ a_s,
                                             float* __restrict__ a_d, int n) {
  int idx = blockIdx.x * 256 + threadIdx.x;
  if (idx >= n * NHEAD) return;
  int nd = idx >> 2, h = idx & 3;
  const float* v = xg + (size_t)nd * (NHEAD * HD) + h * HD;
  const float* as = att_src + h * HD;
  const float* ad = att_dst + h * HD;
  float s1 = 0.f, s2 = 0.f;
#pragma unroll 16
  for (int f = 0; f < HD; ++f) {
    s1 = fmaf(v[f], as[f], s1);
    s2 = fmaf(v[f], ad[f], s2);
  }
  a_s[idx] = s1;
  a_d[idx] = s2;
}

__device__ __forceinline__ float leaky(float v) { return v > 0.f ? v : 0.2f * v; }

#define ONLINE(m, s, e)            \
  do {                             \
    if ((e) > (m)) {               \
      (s) *= expf((m) - (e));      \
      (m) = (e);                   \
    }                              \
    (s) += expf((e) - (m));        \
  } while (0)

// fused GAT: per-node online softmax over incident edges + alpha store + weighted gather
__global__ __launch_bounds__(256) void k_gat(const float* __restrict__ xg,
                                             const float* __restrict__ a_s,
                                             const float* __restrict__ a_d,
                                             const int* __restrict__ csr_src,
                                             const int* __restrict__ row_ptr,
                                             float* __restrict__ alpha,  // [nE][4]
                                             const float* __restrict__ bg,
                                             float* __restrict__ hg, int n) {
  int node = (blockIdx.x * 256 + threadIdx.x) >> 6;
  int lane = threadIdx.x & 63;
  if (node >= n) return;
  int beg = row_ptr[node], end = row_ptr[node + 1];
  float4 ad = ((const float4*)a_d)[node];

  // pass 1: online softmax (lanes stride over edges)
  float m0 = -1e30f, m1 = -1e30f, m2 = -1e30f, m3 = -1e30f;
  float s0 = 0.f, s1 = 0.f, s2 = 0.f, s3 = 0.f;
  for (int i = beg + lane; i < end; i += 64) {
    int s = csr_src[i];
    float4 as = ((const float4*)a_s)[s];
    float e0 = leaky(as.x + ad.x), e1 = leaky(as.y + ad.y);
    float e2 = leaky(as.z + ad.z), e3 = leaky(as.w + ad.w);
    ONLINE(m0, s0, e0);
    ONLINE(m1, s1, e1);
    ONLINE(m2, s2, e2);
    ONLINE(m3, s3, e3);
  }
  // wave-reduce combine (64 lanes)
  for (int o = 1; o < 64; o <<= 1) {
    float mo, so, mn;
    mo = __shfl_xor(m0, o); so = __shfl_xor(s0, o); mn = fmaxf(m0, mo);
    s0 = s0 * expf(m0 - mn) + so * expf(mo - mn); m0 = mn;
    mo = __shfl_xor(m1, o); so = __shfl_xor(s1, o); mn = fmaxf(m1, mo);
    s1 = s1 * expf(m1 - mn) + so * expf(mo - mn); m1 = mn;
    mo = __shfl_xor(m2, o); so = __shfl_xor(s2, o); mn = fmaxf(m2, mo);
    s2 = s2 * expf(m2 - mn) + so * expf(mo - mn); m2 = mn;
    mo = __shfl_xor(m3, o); so = __shfl_xor(s3, o); mn = fmaxf(m3, mo);
    s3 = s3 * expf(m3 - mn) + so * expf(mo - mn); m3 = mn;
  }
  float r0 = 1.f / s0, r1 = 1.f / s1, r2 = 1.f / s2, r3 = 1.f / s3;

  // pass 1b: store normalized alphas (coalesced float4 per edge)
  for (int i = beg + lane; i < end; i += 64) {
    int s = csr_src[i];
    float4 as = ((const float4*)a_s)[s];
    float4 al;
    al.x = expf(leaky(as.x + ad.x) - m0) * r0;
    al.y = expf(leaky(as.y + ad.y) - m1) * r1;
    al.z = expf(leaky(as.z + ad.z) - m2) * r2;
    al.w = expf(leaky(as.w + ad.w) - m3) * r3;
    ((float4*)alpha)[i] = al;
  }

  // pass 2: weighted gather (whole wave per edge; feature = lane)
  float acc0 = 0.f, acc1 = 0.f, acc2 = 0.f, acc3 = 0.f;
  for (int i = beg; i < end; ++i) {
    int s = csr_src[i];                        // uniform
    float4 al = ((const float4*)alpha)[i];     // uniform
    const float* xs = xg + (size_t)s * (NHEAD * HD);
    acc0 = fmaf(xs[lane], al.x, acc0);
    acc1 = fmaf(xs[64 + lane], al.y, acc1);
    acc2 = fmaf(xs[128 + lane], al.z, acc2);
    acc3 = fmaf(xs[192 + lane], al.w, acc3);
  }
  float v = 0.25f * (acc0 + acc1 + acc2 + acc3) + bg[lane];
  hg[(size_t)node * HD + lane] = v;
}

// global feature sum of hg -> gsum[64]
__global__ __launch_bounds__(256) void k_gsum(const float* __restrict__ hg,
                                              float* __restrict__ gsum, int n) {
  __shared__ float red[256];
  int f = threadIdx.x & 63, g = threadIdx.x >> 6;
  float local = 0.f;
  for (int nd = blockIdx.x * 4 + g; nd < n; nd += gridDim.x * 4)
    local += hg[(size_t)nd * HD + f];
  red[threadIdx.x] = local;
  __syncthreads();
  if (threadIdx.x < 64)
    atomicAdd(&gsum[f], red[f] + red[64 + f] + red[128 + f] + red[192 + f]);
}

// tiny classifier head
__global__ __launch_bounds__(64) void k_cls(const float* __restrict__ gsum,
                                            const float* __restrict__ Wc1,
                                            const float* __restrict__ bc1,
                                            const float* __restrict__ Wc2,
                                            const float* __restrict__ bc2,
                                            float* __restrict__ out, int n) {
  __shared__ float hgl[64];
  __shared__ float t1[32];
  int t = threadIdx.x;
  hgl[t] = gsum[t] / (float)n;
  __syncthreads();
  if (t < 32) {
    float a = bc1[t];
#pragma unroll 16
    for (int f = 0; f < 64; ++f) a = fmaf(hgl[f], Wc1[f * 32 + t], a);
    t1[t] = a > 0.f ? a : 0.f;
  }
  __syncthreads();
  if (t < 2) {
    float a = bc2[t];
#pragma unroll
    for (int j = 0; j < 32; ++j) a = fmaf(t1[j], Wc2[j * 2 + t], a);
    out[t] = a;
  }
}

extern "C" void kernel_launch(void* const* d_in, const int* in_sizes, int n_in,
                              void* d_out, int out_size, void* d_ws, size_t ws_size,
                              hipStream_t stream) {
  const float* x = (const float*)d_in[0];
  const int* ei = (const int*)d_in[1];
  const float* W0 = (const float*)d_in[2];
  const float* b0 = (const float*)d_in[3];
  const float* W1 = (const float*)d_in[4];
  const float* b1 = (const float*)d_in[5];
  const float* W2 = (const float*)d_in[6];
  const float* b2 = (const float*)d_in[7];
  const float* Wg = (const float*)d_in[8];
  const float* att_src = (const float*)d_in[9];
  const float* att_dst = (const float*)d_in[10];
  const float* bg = (const float*)d_in[11];
  const float* Wc1 = (const float*)d_in[12];
  const float* bc1 = (const float*)d_in[13];
  const float* Wc2 = (const float*)d_in[14];
  const float* bc2 = (const float*)d_in[15];
  const float* Wr1 = (const float*)d_in[16];
  const float* br1 = (const float*)d_in[17];
  const float* Wr2 = (const float*)d_in[18];
  const float* br2 = (const float*)d_in[19];

  const int n = in_sizes[0] / DIN;  // 50000
  const int E = in_sizes[1] / 2;    // 800000
  const int nE = E + n;
  const int* src = ei;
  const int* dst = ei + E;

  // ---- workspace layout ----
  float* ws = (float*)d_ws;
  size_t off = 0;
  auto alloc = [&](size_t nelems) {
    float* p = ws + off;
    off += (nelems + 63) & ~(size_t)63;
    return p;
  };
  int* CNT = (int*)alloc(n);
  int* BSUM = (int*)alloc(256);
  int* BOFF = (int*)alloc(256);
  int* ROWP = (int*)alloc(n + 1);
  int* CURS = (int*)alloc(n);
  int* CSRS = (int*)alloc(nE);
  float* DINV = alloc(n);
  float* P = alloc((size_t)n * 256);     // GEMM outputs / xg / r1
  float* Hb = alloc((size_t)n * HD);     // hidden h
  float* ASD = alloc((size_t)n * NHEAD);
  float* ADD = alloc((size_t)n * NHEAD);
  float* ALPHA = alloc((size_t)nE * NHEAD);
  float* GSUM = alloc(64);
  (void)ws_size;

  float* out = (float*)d_out;
  float* out_cls = out;                        // 2
  float* out_rec = out + 2;                    // n*256
  float* out_hg = out + 2 + (size_t)n * 256;   // n*64

  const int TB = 256;
  const int B = cdiv(n, TB);  // scan blocks (196)

  // ---- CSR build (by dst, self-loops included) ----
  k_filli<<<cdiv(n, TB), TB, 0, stream>>>(CNT, 1, n);  // self loop
  k_count<<<cdiv(E, TB), TB, 0, stream>>>(dst, CNT, E);
  k_bsum<<<B, TB, 0, stream>>>(CNT, BSUM, n);
  k_bscan<<<1, TB, 0, stream>>>(BSUM, BOFF, B);
  k_rowptr<<<B, TB, 0, stream>>>(CNT, BOFF, ROWP, n, nE);
  k_copyi<<<cdiv(n, TB), TB, 0, stream>>>(ROWP, CURS, n);
  k_csrfill<<<cdiv(nE, TB), TB, 0, stream>>>(src, dst, CURS, CSRS, E, n);
  k_dinv<<<cdiv(n, TB), TB, 0, stream>>>(ROWP, DINV, n);

  // ---- GCN layers ----
  k_gemm<256, 64, 0, 4><<<cdiv(n, 16), TB, 0, stream>>>(x, W0, nullptr, P, n);
  k_agg_csr<<<cdiv((long)n * 64, TB), TB, 0, stream>>>(P, CSRS, ROWP, DINV, b0, nullptr, Hb, n);

  k_gemm<64, 64, 0, 4><<<cdiv(n, 16), TB, 0, stream>>>(Hb, W1, nullptr, P, n);
  k_agg_csr<<<cdiv((long)n * 64, TB), TB, 0, stream>>>(P, CSRS, ROWP, DINV, b1, Hb, Hb, n);

  k_gemm<64, 64, 0, 4><<<cdiv(n, 16), TB, 0, stream>>>(Hb, W2, nullptr, P, n);
  k_agg_csr<<<cdiv((long)n * 64, TB), TB, 0, stream>>>(P, CSRS, ROWP, DINV, b2, Hb, Hb, n);

  // ---- GAT ----
  k_gemm<64, 256, 0, 16><<<cdiv(n, 16), TB, 0, stream>>>(Hb, Wg, nullptr, P, n);  // xg
  k_att<<<cdiv((long)n * NHEAD, TB), TB, 0, stream>>>(P, att_src, att_dst, ASD, ADD, n);
  k_gat<<<cdiv((long)n * 64, TB), TB, 0, stream>>>(P, ASD, ADD, CSRS, ROWP, ALPHA, bg, out_hg, n);

  // ---- global pool + heads ----
  k_fill<<<1, TB, 0, stream>>>(GSUM, 0.f, 64);
  k_gsum<<<512, TB, 0, stream>>>(out_hg, GSUM, n);
  k_cls<<<1, 64, 0, stream>>>(GSUM, Wc1, bc1, Wc2, bc2, out_cls, n);
  k_gemm<64, 64, 1, 4><<<cdiv(n, 16), TB, 0, stream>>>(out_hg, Wr1, br1, P, n);      // r1
  k_gemm<64, 256, 2, 16><<<cdiv(n, 16), TB, 0, stream>>>(P, Wr2, br2, out_rec, n);   // rec
}

// Round 3
// 705.051 us; speedup vs baseline: 2.7852x; 1.4903x over previous
//
#include <hip/hip_runtime.h>

#define DIN 256
#define HD 64
#define NHEAD 4

static inline int cdiv(long a, long b) { return (int)((a + b - 1) / b); }

// ---------------- fills ----------------
__global__ __launch_bounds__(256) void k_fill(float* __restrict__ p, float v, int n) {
  int i = blockIdx.x * 256 + threadIdx.x;
  if (i < n) p[i] = v;
}
__global__ __launch_bounds__(256) void k_filli(int* __restrict__ p, int v, int n) {
  int i = blockIdx.x * 256 + threadIdx.x;
  if (i < n) p[i] = v;
}
__global__ __launch_bounds__(256) void k_copyi(const int* __restrict__ a, int* __restrict__ b, int n) {
  int i = blockIdx.x * 256 + threadIdx.x;
  if (i < n) b[i] = a[i];
}

// ---------------- CSR build ----------------
__global__ __launch_bounds__(256) void k_count(const int* __restrict__ dst,
                                               int* __restrict__ cnt, int E) {
  int i = blockIdx.x * 256 + threadIdx.x;
  if (i < E) atomicAdd(&cnt[dst[i]], 1);
}

__global__ __launch_bounds__(256) void k_bsum(const int* __restrict__ cnt,
                                              int* __restrict__ bsum, int n) {
  __shared__ int sd[256];
  int i = blockIdx.x * 256 + threadIdx.x;
  sd[threadIdx.x] = (i < n) ? cnt[i] : 0;
  __syncthreads();
  for (int o = 128; o > 0; o >>= 1) {
    if (threadIdx.x < o) sd[threadIdx.x] += sd[threadIdx.x + o];
    __syncthreads();
  }
  if (threadIdx.x == 0) bsum[blockIdx.x] = sd[0];
}

__global__ __launch_bounds__(256) void k_bscan(const int* __restrict__ bsum,
                                               int* __restrict__ boff, int B) {
  __shared__ int sd[256];
  int t = threadIdx.x;
  int v = (t < B) ? bsum[t] : 0;
  sd[t] = v;
  __syncthreads();
  for (int o = 1; o < 256; o <<= 1) {
    int x = (t >= o) ? sd[t - o] : 0;
    __syncthreads();
    sd[t] += x;
    __syncthreads();
  }
  if (t < B) boff[t] = sd[t] - v;  // exclusive
}

__global__ __launch_bounds__(256) void k_rowptr(const int* __restrict__ cnt,
                                                const int* __restrict__ boff,
                                                int* __restrict__ row_ptr, int n, int total) {
  __shared__ int sd[256];
  int t = threadIdx.x;
  int i = blockIdx.x * 256 + t;
  int v = (i < n) ? cnt[i] : 0;
  sd[t] = v;
  __syncthreads();
  for (int o = 1; o < 256; o <<= 1) {
    int x = (t >= o) ? sd[t - o] : 0;
    __syncthreads();
    sd[t] += x;
    __syncthreads();
  }
  if (i < n) row_ptr[i] = boff[blockIdx.x] + sd[t] - v;
  if (i == n - 1) row_ptr[n] = total;
}

__global__ __launch_bounds__(256) void k_csrfill(const int* __restrict__ src,
                                                 const int* __restrict__ dst,
                                                 int* __restrict__ cursor,
                                                 int* __restrict__ csr_src, int E, int n) {
  int e = blockIdx.x * 256 + threadIdx.x;
  if (e < E) {
    int pos = atomicAdd(&cursor[dst[e]], 1);
    csr_src[pos] = src[e];
  } else if (e < E + n) {
    int i = e - E;
    int pos = atomicAdd(&cursor[i], 1);
    csr_src[pos] = i;
  }
}

__global__ __launch_bounds__(256) void k_dinv(const int* __restrict__ row_ptr,
                                              float* __restrict__ dinv, int n) {
  int i = blockIdx.x * 256 + threadIdx.x;
  if (i < n) dinv[i] = rsqrtf((float)(row_ptr[i + 1] - row_ptr[i]));
}

// ---------------- tiled GEMM: C[n,KOUT] = A[n,KIN] @ W[KIN,KOUT] ----------------
// 64x64 output tile per block, BK=64, 256 threads, 4x4 microtile per thread.
// MODE 0: plain  1: bias+relu  2: bias  3: plain + fused att dots (a_s,a_d)
template <int KIN, int KOUT, int MODE>
__global__ __launch_bounds__(256) void k_gemm2(const float* __restrict__ A,
                                               const float* __restrict__ W,
                                               const float* __restrict__ bias,
                                               float* __restrict__ C, int n,
                                               const float* __restrict__ attS,
                                               const float* __restrict__ attD,
                                               float* __restrict__ a_s,
                                               float* __restrict__ a_d) {
  constexpr int LD = 68;  // padded LDS stride (floats), keeps float4 alignment
  __shared__ float As[64][LD];
  __shared__ float Ws[64][LD];
  const int tid = threadIdx.x;
  const int tx = tid & 15;        // 0..15 -> output col group (4 cols)
  const int ty = tid >> 4;        // 0..15 -> output row base
  const int m0 = blockIdx.x * 64;
  const int n0 = blockIdx.y * 64;
  const int lr = tid >> 4;        // load row 0..15 (stride 16)
  const int lc = (tid & 15) * 4;  // load col (float4)
  float acc[4][4] = {};

  for (int k0 = 0; k0 < KIN; k0 += 64) {
#pragma unroll
    for (int q = 0; q < 4; ++q) {
      int r = lr + q * 16;
      int gr = m0 + r;
      gr = gr < n ? gr : n - 1;
      *(float4*)&As[r][lc] = *(const float4*)(A + (size_t)gr * KIN + k0 + lc);
      *(float4*)&Ws[r][lc] = *(const float4*)(W + (size_t)(k0 + r) * KOUT + n0 + lc);
    }
    __syncthreads();
#pragma unroll
    for (int k = 0; k < 64; k += 4) {
      // thread's rows: ty + 16*i  (bank-conflict-free: 4 addrs stride 68)
      float4 a0 = *(const float4*)&As[ty][k];
      float4 a1 = *(const float4*)&As[ty + 16][k];
      float4 a2 = *(const float4*)&As[ty + 32][k];
      float4 a3 = *(const float4*)&As[ty + 48][k];
      float4 w0 = *(const float4*)&Ws[k + 0][tx * 4];
      float4 w1 = *(const float4*)&Ws[k + 1][tx * 4];
      float4 w2 = *(const float4*)&Ws[k + 2][tx * 4];
      float4 w3 = *(const float4*)&Ws[k + 3][tx * 4];
#define FMA_ROW(i, av)                                                   \
      acc[i][0] = fmaf(av.x, w0.x, fmaf(av.y, w1.x, fmaf(av.z, w2.x, fmaf(av.w, w3.x, acc[i][0])))); \
      acc[i][1] = fmaf(av.x, w0.y, fmaf(av.y, w1.y, fmaf(av.z, w2.y, fmaf(av.w, w3.y, acc[i][1])))); \
      acc[i][2] = fmaf(av.x, w0.z, fmaf(av.y, w1.z, fmaf(av.z, w2.z, fmaf(av.w, w3.z, acc[i][2])))); \
      acc[i][3] = fmaf(av.x, w0.w, fmaf(av.y, w1.w, fmaf(av.z, w2.w, fmaf(av.w, w3.w, acc[i][3]))));
      FMA_ROW(0, a0)
      FMA_ROW(1, a1)
      FMA_ROW(2, a2)
      FMA_ROW(3, a3)
#undef FMA_ROW
    }
    __syncthreads();
  }

  float4 bv = {0.f, 0.f, 0.f, 0.f};
  if (MODE == 1 || MODE == 2) bv = *(const float4*)(bias + n0 + tx * 4);
  float4 attsv = {0.f, 0.f, 0.f, 0.f}, attdv = {0.f, 0.f, 0.f, 0.f};
  if (MODE == 3) {
    attsv = *(const float4*)(attS + blockIdx.y * 64 + tx * 4);
    attdv = *(const float4*)(attD + blockIdx.y * 64 + tx * 4);
  }
#pragma unroll
  for (int i = 0; i < 4; ++i) {
    int gr = m0 + ty + 16 * i;
    float4 r;
    r.x = acc[i][0]; r.y = acc[i][1]; r.z = acc[i][2]; r.w = acc[i][3];
    if (MODE == 1 || MODE == 2) {
      r.x += bv.x; r.y += bv.y; r.z += bv.z; r.w += bv.w;
      if (MODE == 1) {
        r.x = r.x > 0.f ? r.x : 0.f; r.y = r.y > 0.f ? r.y : 0.f;
        r.z = r.z > 0.f ? r.z : 0.f; r.w = r.w > 0.f ? r.w : 0.f;
      }
    }
    if (gr < n) *(float4*)(C + (size_t)gr * KOUT + n0 + tx * 4) = r;
    if (MODE == 3) {
      float pds = r.x * attsv.x + r.y * attsv.y + r.z * attsv.z + r.w * attsv.w;
      float pdd = r.x * attdv.x + r.y * attdv.y + r.z * attdv.z + r.w * attdv.w;
#pragma unroll
      for (int o = 8; o > 0; o >>= 1) {
        pds += __shfl_down(pds, o);
        pdd += __shfl_down(pdd, o);
      }
      if (tx == 0 && gr < n) {
        a_s[gr * NHEAD + blockIdx.y] = pds;
        a_d[gr * NHEAD + blockIdx.y] = pdd;
      }
    }
  }
}

// ---------------- GCN aggregation (CSR gather) ----------------
__global__ __launch_bounds__(256) void k_agg_csr(const float* __restrict__ P,
                                                 const int* __restrict__ csr_src,
                                                 const int* __restrict__ row_ptr,
                                                 const float* __restrict__ dinv,
                                                 const float* __restrict__ bias,
                                                 const float* __restrict__ resid,
                                                 float* __restrict__ out, int n) {
  int node = (blockIdx.x * 256 + threadIdx.x) >> 6;
  int lane = threadIdx.x & 63;
  if (node >= n) return;
  int beg = row_ptr[node], end = row_ptr[node + 1];
  float acc = 0.f;
  for (int i = beg; i < end; ++i) {
    int s = csr_src[i];  // wave-uniform broadcast
    acc = fmaf(P[(size_t)s * HD + lane], dinv[s], acc);
  }
  float v = acc * dinv[node] + bias[lane];
  v = v > 0.f ? v : 0.f;
  if (resid) v += resid[(size_t)node * HD + lane];
  out[(size_t)node * HD + lane] = v;
}

// ---------------- GAT: fused segment softmax + gather ----------------
__device__ __forceinline__ float leaky(float v) { return v > 0.f ? v : 0.2f * v; }

__global__ __launch_bounds__(256) void k_gat(const float* __restrict__ xg,
                                             const float* __restrict__ a_s,
                                             const float* __restrict__ a_d,
                                             const int* __restrict__ csr_src,
                                             const int* __restrict__ row_ptr,
                                             float* __restrict__ galpha,  // [nE][4] fallback
                                             const float* __restrict__ bg,
                                             float* __restrict__ hg, int n) {
  __shared__ float4 ew[4][128];
  const int wid = threadIdx.x >> 6;
  const int node = (blockIdx.x * 256 + threadIdx.x) >> 6;
  const int lane = threadIdx.x & 63;
  if (node >= n) return;
  const int beg = row_ptr[node], end = row_ptr[node + 1];
  const bool uselds = (end - beg) <= 128;
  float4 ad = ((const float4*)a_d)[node];

  // P1: edge logits + lane-local max (no exp)
  float m0 = -1e30f, m1 = -1e30f, m2 = -1e30f, m3 = -1e30f;
  for (int i = beg + lane; i < end; i += 64) {
    int s = csr_src[i];
    float4 as = ((const float4*)a_s)[s];
    float4 e;
    e.x = leaky(as.x + ad.x); e.y = leaky(as.y + ad.y);
    e.z = leaky(as.z + ad.z); e.w = leaky(as.w + ad.w);
    if (uselds) ew[wid][i - beg] = e; else ((float4*)galpha)[i] = e;
    m0 = fmaxf(m0, e.x); m1 = fmaxf(m1, e.y);
    m2 = fmaxf(m2, e.z); m3 = fmaxf(m3, e.w);
  }
  if (!uselds) __threadfence();
#pragma unroll
  for (int o = 32; o > 0; o >>= 1) {
    m0 = fmaxf(m0, __shfl_xor(m0, o));
    m1 = fmaxf(m1, __shfl_xor(m1, o));
    m2 = fmaxf(m2, __shfl_xor(m2, o));
    m3 = fmaxf(m3, __shfl_xor(m3, o));
  }

  // P2: exp + lane-local sum
  float s0 = 0.f, s1 = 0.f, s2 = 0.f, s3 = 0.f;
  for (int i = beg + lane; i < end; i += 64) {
    float4 e = uselds ? ew[wid][i - beg] : ((const float4*)galpha)[i];
    float4 ex;
    ex.x = expf(e.x - m0); ex.y = expf(e.y - m1);
    ex.z = expf(e.z - m2); ex.w = expf(e.w - m3);
    if (uselds) ew[wid][i - beg] = ex; else ((float4*)galpha)[i] = ex;
    s0 += ex.x; s1 += ex.y; s2 += ex.z; s3 += ex.w;
  }
  if (!uselds) __threadfence();
#pragma unroll
  for (int o = 32; o > 0; o >>= 1) {
    s0 += __shfl_xor(s0, o);
    s1 += __shfl_xor(s1, o);
    s2 += __shfl_xor(s2, o);
    s3 += __shfl_xor(s3, o);
  }
  float r0 = 0.25f / s0, r1 = 0.25f / s1, r2 = 0.25f / s2, r3 = 0.25f / s3;

  // P3: uniform weighted gather; normalization folded into final scale
  float acc0 = 0.f, acc1 = 0.f, acc2 = 0.f, acc3 = 0.f;
  for (int i = beg; i < end; ++i) {
    int s = csr_src[i];                                       // uniform
    float4 al = uselds ? ew[wid][i - beg] : ((const float4*)galpha)[i];  // uniform
    const float* xs = xg + (size_t)s * (NHEAD * HD);
    acc0 = fmaf(xs[lane], al.x, acc0);
    acc1 = fmaf(xs[64 + lane], al.y, acc1);
    acc2 = fmaf(xs[128 + lane], al.z, acc2);
    acc3 = fmaf(xs[192 + lane], al.w, acc3);
  }
  hg[(size_t)node * HD + lane] =
      acc0 * r0 + acc1 * r1 + acc2 * r2 + acc3 * r3 + bg[lane];
}

// global feature sum of hg -> gsum[64]
__global__ __launch_bounds__(256) void k_gsum(const float* __restrict__ hg,
                                              float* __restrict__ gsum, int n) {
  __shared__ float red[256];
  int f = threadIdx.x & 63, g = threadIdx.x >> 6;
  float local = 0.f;
  for (int nd = blockIdx.x * 4 + g; nd < n; nd += gridDim.x * 4)
    local += hg[(size_t)nd * HD + f];
  red[threadIdx.x] = local;
  __syncthreads();
  if (threadIdx.x < 64)
    atomicAdd(&gsum[f], red[f] + red[64 + f] + red[128 + f] + red[192 + f]);
}

// tiny classifier head
__global__ __launch_bounds__(64) void k_cls(const float* __restrict__ gsum,
                                            const float* __restrict__ Wc1,
                                            const float* __restrict__ bc1,
                                            const float* __restrict__ Wc2,
                                            const float* __restrict__ bc2,
                                            float* __restrict__ out, int n) {
  __shared__ float hgl[64];
  __shared__ float t1[32];
  int t = threadIdx.x;
  hgl[t] = gsum[t] / (float)n;
  __syncthreads();
  if (t < 32) {
    float a = bc1[t];
#pragma unroll 16
    for (int f = 0; f < 64; ++f) a = fmaf(hgl[f], Wc1[f * 32 + t], a);
    t1[t] = a > 0.f ? a : 0.f;
  }
  __syncthreads();
  if (t < 2) {
    float a = bc2[t];
#pragma unroll
    for (int j = 0; j < 32; ++j) a = fmaf(t1[j], Wc2[j * 2 + t], a);
    out[t] = a;
  }
}

extern "C" void kernel_launch(void* const* d_in, const int* in_sizes, int n_in,
                              void* d_out, int out_size, void* d_ws, size_t ws_size,
                              hipStream_t stream) {
  const float* x = (const float*)d_in[0];
  const int* ei = (const int*)d_in[1];
  const float* W0 = (const float*)d_in[2];
  const float* b0 = (const float*)d_in[3];
  const float* W1 = (const float*)d_in[4];
  const float* b1 = (const float*)d_in[5];
  const float* W2 = (const float*)d_in[6];
  const float* b2 = (const float*)d_in[7];
  const float* Wg = (const float*)d_in[8];
  const float* att_src = (const float*)d_in[9];
  const float* att_dst = (const float*)d_in[10];
  const float* bg = (const float*)d_in[11];
  const float* Wc1 = (const float*)d_in[12];
  const float* bc1 = (const float*)d_in[13];
  const float* Wc2 = (const float*)d_in[14];
  const float* bc2 = (const float*)d_in[15];
  const float* Wr1 = (const float*)d_in[16];
  const float* br1 = (const float*)d_in[17];
  const float* Wr2 = (const float*)d_in[18];
  const float* br2 = (const float*)d_in[19];

  const int n = in_sizes[0] / DIN;  // 50000
  const int E = in_sizes[1] / 2;    // 800000
  const int nE = E + n;
  const int* src = ei;
  const int* dst = ei + E;

  // ---- workspace layout ----
  float* ws = (float*)d_ws;
  size_t off = 0;
  auto alloc = [&](size_t nelems) {
    float* p = ws + off;
    off += (nelems + 63) & ~(size_t)63;
    return p;
  };
  int* CNT = (int*)alloc(n);
  int* BSUM = (int*)alloc(256);
  int* BOFF = (int*)alloc(256);
  int* ROWP = (int*)alloc(n + 1);
  int* CURS = (int*)alloc(n);
  int* CSRS = (int*)alloc(nE);
  float* DINV = alloc(n);
  float* P = alloc((size_t)n * 256);   // GEMM outputs / xg / r1
  float* Hb = alloc((size_t)n * HD);   // hidden h
  float* ASD = alloc((size_t)n * NHEAD);
  float* ADD = alloc((size_t)n * NHEAD);
  float* GALPHA = alloc((size_t)nE * NHEAD);  // deg>128 fallback only
  float* GSUM = alloc(64);
  (void)ws_size;

  float* out = (float*)d_out;
  float* out_cls = out;                       // 2
  float* out_rec = out + 2;                   // n*256
  float* out_hg = out + 2 + (size_t)n * 256;  // n*64

  const int TB = 256;
  const int B = cdiv(n, TB);
  const int GM = cdiv(n, 64);  // GEMM M-tiles (782)

  // ---- CSR build (by dst, self-loops included) ----
  k_filli<<<cdiv(n, TB), TB, 0, stream>>>(CNT, 1, n);  // self loop
  k_count<<<cdiv(E, TB), TB, 0, stream>>>(dst, CNT, E);
  k_bsum<<<B, TB, 0, stream>>>(CNT, BSUM, n);
  k_bscan<<<1, TB, 0, stream>>>(BSUM, BOFF, B);
  k_rowptr<<<B, TB, 0, stream>>>(CNT, BOFF, ROWP, n, nE);
  k_copyi<<<cdiv(n, TB), TB, 0, stream>>>(ROWP, CURS, n);
  k_csrfill<<<cdiv(nE, TB), TB, 0, stream>>>(src, dst, CURS, CSRS, E, n);
  k_dinv<<<cdiv(n, TB), TB, 0, stream>>>(ROWP, DINV, n);

  // ---- GCN layers ----
  k_gemm2<256, 64, 0><<<dim3(GM, 1), TB, 0, stream>>>(x, W0, nullptr, P, n,
                                                      nullptr, nullptr, nullptr, nullptr);
  k_agg_csr<<<cdiv((long)n * 64, TB), TB, 0, stream>>>(P, CSRS, ROWP, DINV, b0, nullptr, Hb, n);

  k_gemm2<64, 64, 0><<<dim3(GM, 1), TB, 0, stream>>>(Hb, W1, nullptr, P, n,
                                                     nullptr, nullptr, nullptr, nullptr);
  k_agg_csr<<<cdiv((long)n * 64, TB), TB, 0, stream>>>(P, CSRS, ROWP, DINV, b1, Hb, Hb, n);

  k_gemm2<64, 64, 0><<<dim3(GM, 1), TB, 0, stream>>>(Hb, W2, nullptr, P, n,
                                                     nullptr, nullptr, nullptr, nullptr);
  k_agg_csr<<<cdiv((long)n * 64, TB), TB, 0, stream>>>(P, CSRS, ROWP, DINV, b2, Hb, Hb, n);

  // ---- GAT (att dots fused into GEMM epilogue) ----
  k_gemm2<64, 256, 3><<<dim3(GM, 4), TB, 0, stream>>>(Hb, Wg, nullptr, P, n,
                                                      att_src, att_dst, ASD, ADD);
  k_gat<<<cdiv((long)n * 64, TB), TB, 0, stream>>>(P, ASD, ADD, CSRS, ROWP, GALPHA, bg, out_hg, n);

  // ---- global pool + heads ----
  k_fill<<<1, TB, 0, stream>>>(GSUM, 0.f, 64);
  k_gsum<<<512, TB, 0, stream>>>(out_hg, GSUM, n);
  k_cls<<<1, 64, 0, stream>>>(GSUM, Wc1, bc1, Wc2, bc2, out_cls, n);
  k_gemm2<64, 64, 1><<<dim3(GM, 1), TB, 0, stream>>>(out_hg, Wr1, br1, P, n,
                                                     nullptr, nullptr, nullptr, nullptr);
  k_gemm2<64, 256, 2><<<dim3(GM, 4), TB, 0, stream>>>(P, Wr2, br2, out_rec, n,
                                                      nullptr, nullptr, nullptr, nullptr);
}

// Round 4
// 548.448 us; speedup vs baseline: 3.5805x; 1.2855x over previous
//
#include <hip/hip_runtime.h>

#define DIN 256
#define HD 64
#define NHEAD 4

static inline int cdiv(long a, long b) { return (int)((a + b - 1) / b); }

// ---------------- fills ----------------
__global__ __launch_bounds__(256) void k_fill(float* __restrict__ p, float v, int n) {
  int i = blockIdx.x * 256 + threadIdx.x;
  if (i < n) p[i] = v;
}
__global__ __launch_bounds__(256) void k_filli(int* __restrict__ p, int v, int n) {
  int i = blockIdx.x * 256 + threadIdx.x;
  if (i < n) p[i] = v;
}
__global__ __launch_bounds__(256) void k_copyi(const int* __restrict__ a, int* __restrict__ b, int n) {
  int i = blockIdx.x * 256 + threadIdx.x;
  if (i < n) b[i] = a[i];
}

// ---------------- CSR build ----------------
__global__ __launch_bounds__(256) void k_count(const int* __restrict__ dst,
                                               int* __restrict__ cnt, int E) {
  int i = blockIdx.x * 256 + threadIdx.x;
  if (i < E) atomicAdd(&cnt[dst[i]], 1);
}

__global__ __launch_bounds__(256) void k_bsum(const int* __restrict__ cnt,
                                              int* __restrict__ bsum, int n) {
  __shared__ int sd[256];
  int i = blockIdx.x * 256 + threadIdx.x;
  sd[threadIdx.x] = (i < n) ? cnt[i] : 0;
  __syncthreads();
  for (int o = 128; o > 0; o >>= 1) {
    if (threadIdx.x < o) sd[threadIdx.x] += sd[threadIdx.x + o];
    __syncthreads();
  }
  if (threadIdx.x == 0) bsum[blockIdx.x] = sd[0];
}

__global__ __launch_bounds__(256) void k_bscan(const int* __restrict__ bsum,
                                               int* __restrict__ boff, int B) {
  __shared__ int sd[256];
  int t = threadIdx.x;
  int v = (t < B) ? bsum[t] : 0;
  sd[t] = v;
  __syncthreads();
  for (int o = 1; o < 256; o <<= 1) {
    int x = (t >= o) ? sd[t - o] : 0;
    __syncthreads();
    sd[t] += x;
    __syncthreads();
  }
  if (t < B) boff[t] = sd[t] - v;  // exclusive
}

__global__ __launch_bounds__(256) void k_rowptr(const int* __restrict__ cnt,
                                                const int* __restrict__ boff,
                                                int* __restrict__ row_ptr, int n, int total) {
  __shared__ int sd[256];
  int t = threadIdx.x;
  int i = blockIdx.x * 256 + t;
  int v = (i < n) ? cnt[i] : 0;
  sd[t] = v;
  __syncthreads();
  for (int o = 1; o < 256; o <<= 1) {
    int x = (t >= o) ? sd[t - o] : 0;
    __syncthreads();
    sd[t] += x;
    __syncthreads();
  }
  if (i < n) row_ptr[i] = boff[blockIdx.x] + sd[t] - v;
  if (i == n - 1) row_ptr[n] = total;
}

__global__ __launch_bounds__(256) void k_csrfill(const int* __restrict__ src,
                                                 const int* __restrict__ dst,
                                                 int* __restrict__ cursor,
                                                 int* __restrict__ csr_src, int E, int n) {
  int e = blockIdx.x * 256 + threadIdx.x;
  if (e < E) {
    int pos = atomicAdd(&cursor[dst[e]], 1);
    csr_src[pos] = src[e];
  } else if (e < E + n) {
    int i = e - E;
    int pos = atomicAdd(&cursor[i], 1);
    csr_src[pos] = i;
  }
}

__global__ __launch_bounds__(256) void k_dinv(const int* __restrict__ row_ptr,
                                              float* __restrict__ dinv, int n) {
  int i = blockIdx.x * 256 + threadIdx.x;
  if (i < n) dinv[i] = rsqrtf((float)(row_ptr[i + 1] - row_ptr[i]));
}

// ---------------- tiled GEMM: C[n,KOUT] = A[n,KIN] @ W[KIN,KOUT] ----------------
// 64x64 output tile per block, BK=64, 256 threads, 4x4 microtile per thread.
// MODE 0: plain  1: bias+relu  2: bias (float2 stores, C only 8B-aligned)
// MODE 3: plain + fused att dots (a_s,a_d)
template <int KIN, int KOUT, int MODE>
__global__ __launch_bounds__(256, 4) void k_gemm2(const float* __restrict__ A,
                                                  const float* __restrict__ W,
                                                  const float* __restrict__ bias,
                                                  float* __restrict__ C, int n,
                                                  const float* __restrict__ attS,
                                                  const float* __restrict__ attD,
                                                  float* __restrict__ a_s,
                                                  float* __restrict__ a_d) {
  constexpr int LD = 68;  // padded LDS stride (floats), keeps float4 alignment
  __shared__ float As[64][LD];
  __shared__ float Ws[64][LD];
  const int tid = threadIdx.x;
  const int tx = tid & 15;        // 0..15 -> output col group (4 cols)
  const int ty = tid >> 4;        // 0..15 -> output row base
  const int m0 = blockIdx.x * 64;
  const int n0 = blockIdx.y * 64;
  const int lr = tid >> 4;        // load row 0..15 (stride 16)
  const int lc = (tid & 15) * 4;  // load col (float4)
  float acc[4][4] = {};

  for (int k0 = 0; k0 < KIN; k0 += 64) {
#pragma unroll
    for (int q = 0; q < 4; ++q) {
      int r = lr + q * 16;
      int gr = m0 + r;
      gr = gr < n ? gr : n - 1;
      *(float4*)&As[r][lc] = *(const float4*)(A + (size_t)gr * KIN + k0 + lc);
      *(float4*)&Ws[r][lc] = *(const float4*)(W + (size_t)(k0 + r) * KOUT + n0 + lc);
    }
    __syncthreads();
#pragma unroll 2
    for (int k = 0; k < 64; k += 4) {
      float4 a0 = *(const float4*)&As[ty][k];
      float4 a1 = *(const float4*)&As[ty + 16][k];
      float4 a2 = *(const float4*)&As[ty + 32][k];
      float4 a3 = *(const float4*)&As[ty + 48][k];
      float4 w0 = *(const float4*)&Ws[k + 0][tx * 4];
      float4 w1 = *(const float4*)&Ws[k + 1][tx * 4];
      float4 w2 = *(const float4*)&Ws[k + 2][tx * 4];
      float4 w3 = *(const float4*)&Ws[k + 3][tx * 4];
#define FMA_ROW(i, av)                                                   \
      acc[i][0] = fmaf(av.x, w0.x, fmaf(av.y, w1.x, fmaf(av.z, w2.x, fmaf(av.w, w3.x, acc[i][0])))); \
      acc[i][1] = fmaf(av.x, w0.y, fmaf(av.y, w1.y, fmaf(av.z, w2.y, fmaf(av.w, w3.y, acc[i][1])))); \
      acc[i][2] = fmaf(av.x, w0.z, fmaf(av.y, w1.z, fmaf(av.z, w2.z, fmaf(av.w, w3.z, acc[i][2])))); \
      acc[i][3] = fmaf(av.x, w0.w, fmaf(av.y, w1.w, fmaf(av.z, w2.w, fmaf(av.w, w3.w, acc[i][3]))));
      FMA_ROW(0, a0)
      FMA_ROW(1, a1)
      FMA_ROW(2, a2)
      FMA_ROW(3, a3)
#undef FMA_ROW
    }
    __syncthreads();
  }

  float4 bv = {0.f, 0.f, 0.f, 0.f};
  if (MODE == 1 || MODE == 2) bv = *(const float4*)(bias + n0 + tx * 4);
  float4 attsv = {0.f, 0.f, 0.f, 0.f}, attdv = {0.f, 0.f, 0.f, 0.f};
  if (MODE == 3) {
    attsv = *(const float4*)(attS + blockIdx.y * 64 + tx * 4);
    attdv = *(const float4*)(attD + blockIdx.y * 64 + tx * 4);
  }
#pragma unroll
  for (int i = 0; i < 4; ++i) {
    int gr = m0 + ty + 16 * i;
    float4 r;
    r.x = acc[i][0]; r.y = acc[i][1]; r.z = acc[i][2]; r.w = acc[i][3];
    if (MODE == 1 || MODE == 2) {
      r.x += bv.x; r.y += bv.y; r.z += bv.z; r.w += bv.w;
      if (MODE == 1) {
        r.x = r.x > 0.f ? r.x : 0.f; r.y = r.y > 0.f ? r.y : 0.f;
        r.z = r.z > 0.f ? r.z : 0.f; r.w = r.w > 0.f ? r.w : 0.f;
      }
    }
    if (gr < n) {
      if (MODE == 2) {  // C only 8B-aligned (d_out + 2 floats)
        float2 lo; lo.x = r.x; lo.y = r.y;
        float2 hi; hi.x = r.z; hi.y = r.w;
        *(float2*)(C + (size_t)gr * KOUT + n0 + tx * 4) = lo;
        *(float2*)(C + (size_t)gr * KOUT + n0 + tx * 4 + 2) = hi;
      } else {
        *(float4*)(C + (size_t)gr * KOUT + n0 + tx * 4) = r;
      }
    }
    if (MODE == 3) {
      float pds = r.x * attsv.x + r.y * attsv.y + r.z * attsv.z + r.w * attsv.w;
      float pdd = r.x * attdv.x + r.y * attdv.y + r.z * attdv.z + r.w * attdv.w;
#pragma unroll
      for (int o = 8; o > 0; o >>= 1) {
        pds += __shfl_down(pds, o);
        pdd += __shfl_down(pdd, o);
      }
      if (tx == 0 && gr < n) {
        a_s[gr * NHEAD + blockIdx.y] = pds;
        a_d[gr * NHEAD + blockIdx.y] = pdd;
      }
    }
  }
}

// ---------------- GCN aggregation (CSR gather), 2-edge unroll ----------------
__global__ __launch_bounds__(256) void k_agg_csr(const float* __restrict__ P,
                                                 const int* __restrict__ csr_src,
                                                 const int* __restrict__ row_ptr,
                                                 const float* __restrict__ dinv,
                                                 const float* __restrict__ bias,
                                                 const float* __restrict__ resid,
                                                 float* __restrict__ out, int n) {
  int node = (blockIdx.x * 256 + threadIdx.x) >> 6;
  int lane = threadIdx.x & 63;
  if (node >= n) return;
  int beg = row_ptr[node], end = row_ptr[node + 1];
  float accA = 0.f, accB = 0.f;
  int i = beg;
  for (; i + 2 <= end; i += 2) {
    int s0 = csr_src[i], s1 = csr_src[i + 1];
    float d0 = dinv[s0], d1 = dinv[s1];
    float v0 = P[(size_t)s0 * HD + lane];
    float v1 = P[(size_t)s1 * HD + lane];
    accA = fmaf(v0, d0, accA);
    accB = fmaf(v1, d1, accB);
  }
  if (i < end) {
    int s = csr_src[i];
    accA = fmaf(P[(size_t)s * HD + lane], dinv[s], accA);
  }
  float v = (accA + accB) * dinv[node] + bias[lane];
  v = v > 0.f ? v : 0.f;
  if (resid) v += resid[(size_t)node * HD + lane];
  out[(size_t)node * HD + lane] = v;
}

// ---------------- GAT: fused segment softmax + gather ----------------
__device__ __forceinline__ float leaky(float v) { return v > 0.f ? v : 0.2f * v; }

__global__ __launch_bounds__(256) void k_gat(const float* __restrict__ xg,
                                             const float* __restrict__ a_s,
                                             const float* __restrict__ a_d,
                                             const int* __restrict__ csr_src,
                                             const int* __restrict__ row_ptr,
                                             float* __restrict__ galpha,  // [nE][4] fallback
                                             const float* __restrict__ bg,
                                             float* __restrict__ hg,      // d_out slice (scalar ok)
                                             float* __restrict__ hga,     // aligned ws copy
                                             int n) {
  __shared__ float4 ew[4][128];
  const int wid = threadIdx.x >> 6;
  const int node = (blockIdx.x * 256 + threadIdx.x) >> 6;
  const int lane = threadIdx.x & 63;
  if (node >= n) return;
  const int beg = row_ptr[node], end = row_ptr[node + 1];
  const bool uselds = (end - beg) <= 128;
  float4 ad = ((const float4*)a_d)[node];

  // P1: edge logits + lane-local max (no exp)
  float m0 = -1e30f, m1 = -1e30f, m2 = -1e30f, m3 = -1e30f;
  for (int i = beg + lane; i < end; i += 64) {
    int s = csr_src[i];
    float4 as = ((const float4*)a_s)[s];
    float4 e;
    e.x = leaky(as.x + ad.x); e.y = leaky(as.y + ad.y);
    e.z = leaky(as.z + ad.z); e.w = leaky(as.w + ad.w);
    if (uselds) ew[wid][i - beg] = e; else ((float4*)galpha)[i] = e;
    m0 = fmaxf(m0, e.x); m1 = fmaxf(m1, e.y);
    m2 = fmaxf(m2, e.z); m3 = fmaxf(m3, e.w);
  }
  if (!uselds) __threadfence();
#pragma unroll
  for (int o = 32; o > 0; o >>= 1) {
    m0 = fmaxf(m0, __shfl_xor(m0, o));
    m1 = fmaxf(m1, __shfl_xor(m1, o));
    m2 = fmaxf(m2, __shfl_xor(m2, o));
    m3 = fmaxf(m3, __shfl_xor(m3, o));
  }

  // P2: exp + lane-local sum
  float s0 = 0.f, s1 = 0.f, s2 = 0.f, s3 = 0.f;
  for (int i = beg + lane; i < end; i += 64) {
    float4 e = uselds ? ew[wid][i - beg] : ((const float4*)galpha)[i];
    float4 ex;
    ex.x = expf(e.x - m0); ex.y = expf(e.y - m1);
    ex.z = expf(e.z - m2); ex.w = expf(e.w - m3);
    if (uselds) ew[wid][i - beg] = ex; else ((float4*)galpha)[i] = ex;
    s0 += ex.x; s1 += ex.y; s2 += ex.z; s3 += ex.w;
  }
  if (!uselds) __threadfence();
#pragma unroll
  for (int o = 32; o > 0; o >>= 1) {
    s0 += __shfl_xor(s0, o);
    s1 += __shfl_xor(s1, o);
    s2 += __shfl_xor(s2, o);
    s3 += __shfl_xor(s3, o);
  }
  float r0 = 0.25f / s0, r1 = 0.25f / s1, r2 = 0.25f / s2, r3 = 0.25f / s3;

  // P3: uniform weighted gather (2-edge unroll); normalization folded at end
  float acc0 = 0.f, acc1 = 0.f, acc2 = 0.f, acc3 = 0.f;
  float bcc0 = 0.f, bcc1 = 0.f, bcc2 = 0.f, bcc3 = 0.f;
  int i = beg;
  for (; i + 2 <= end; i += 2) {
    int sA = csr_src[i], sB = csr_src[i + 1];
    float4 alA = uselds ? ew[wid][i - beg] : ((const float4*)galpha)[i];
    float4 alB = uselds ? ew[wid][i + 1 - beg] : ((const float4*)galpha)[i + 1];
    const float* xA = xg + (size_t)sA * (NHEAD * HD);
    const float* xB = xg + (size_t)sB * (NHEAD * HD);
    acc0 = fmaf(xA[lane], alA.x, acc0);
    bcc0 = fmaf(xB[lane], alB.x, bcc0);
    acc1 = fmaf(xA[64 + lane], alA.y, acc1);
    bcc1 = fmaf(xB[64 + lane], alB.y, bcc1);
    acc2 = fmaf(xA[128 + lane], alA.z, acc2);
    bcc2 = fmaf(xB[128 + lane], alB.z, bcc2);
    acc3 = fmaf(xA[192 + lane], alA.w, acc3);
    bcc3 = fmaf(xB[192 + lane], alB.w, bcc3);
  }
  if (i < end) {
    int s = csr_src[i];
    float4 al = uselds ? ew[wid][i - beg] : ((const float4*)galpha)[i];
    const float* xs = xg + (size_t)s * (NHEAD * HD);
    acc0 = fmaf(xs[lane], al.x, acc0);
    acc1 = fmaf(xs[64 + lane], al.y, acc1);
    acc2 = fmaf(xs[128 + lane], al.z, acc2);
    acc3 = fmaf(xs[192 + lane], al.w, acc3);
  }
  float v = (acc0 + bcc0) * r0 + (acc1 + bcc1) * r1 +
            (acc2 + bcc2) * r2 + (acc3 + bcc3) * r3 + bg[lane];
  hg[(size_t)node * HD + lane] = v;
  hga[(size_t)node * HD + lane] = v;
}

// global feature sum of hg -> gsum[64]
__global__ __launch_bounds__(256) void k_gsum(const float* __restrict__ hg,
                                              float* __restrict__ gsum, int n) {
  __shared__ float red[256];
  int f = threadIdx.x & 63, g = threadIdx.x >> 6;
  float local = 0.f;
  for (int nd = blockIdx.x * 4 + g; nd < n; nd += gridDim.x * 4)
    local += hg[(size_t)nd * HD + f];
  red[threadIdx.x] = local;
  __syncthreads();
  if (threadIdx.x < 64)
    atomicAdd(&gsum[f], red[f] + red[64 + f] + red[128 + f] + red[192 + f]);
}

// tiny classifier head
__global__ __launch_bounds__(64) void k_cls(const float* __restrict__ gsum,
                                            const float* __restrict__ Wc1,
                                            const float* __restrict__ bc1,
                                            const float* __restrict__ Wc2,
                                            const float* __restrict__ bc2,
                                            float* __restrict__ out, int n) {
  __shared__ float hgl[64];
  __shared__ float t1[32];
  int t = threadIdx.x;
  hgl[t] = gsum[t] / (float)n;
  __syncthreads();
  if (t < 32) {
    float a = bc1[t];
#pragma unroll 16
    for (int f = 0; f < 64; ++f) a = fmaf(hgl[f], Wc1[f * 32 + t], a);
    t1[t] = a > 0.f ? a : 0.f;
  }
  __syncthreads();
  if (t < 2) {
    float a = bc2[t];
#pragma unroll
    for (int j = 0; j < 32; ++j) a = fmaf(t1[j], Wc2[j * 2 + t], a);
    out[t] = a;
  }
}

extern "C" void kernel_launch(void* const* d_in, const int* in_sizes, int n_in,
                              void* d_out, int out_size, void* d_ws, size_t ws_size,
                              hipStream_t stream) {
  const float* x = (const float*)d_in[0];
  const int* ei = (const int*)d_in[1];
  const float* W0 = (const float*)d_in[2];
  const float* b0 = (const float*)d_in[3];
  const float* W1 = (const float*)d_in[4];
  const float* b1 = (const float*)d_in[5];
  const float* W2 = (const float*)d_in[6];
  const float* b2 = (const float*)d_in[7];
  const float* Wg = (const float*)d_in[8];
  const float* att_src = (const float*)d_in[9];
  const float* att_dst = (const float*)d_in[10];
  const float* bg = (const float*)d_in[11];
  const float* Wc1 = (const float*)d_in[12];
  const float* bc1 = (const float*)d_in[13];
  const float* Wc2 = (const float*)d_in[14];
  const float* bc2 = (const float*)d_in[15];
  const float* Wr1 = (const float*)d_in[16];
  const float* br1 = (const float*)d_in[17];
  const float* Wr2 = (const float*)d_in[18];
  const float* br2 = (const float*)d_in[19];

  const int n = in_sizes[0] / DIN;  // 50000
  const int E = in_sizes[1] / 2;    // 800000
  const int nE = E + n;
  const int* src = ei;
  const int* dst = ei + E;

  // ---- workspace layout ----
  float* ws = (float*)d_ws;
  size_t off = 0;
  auto alloc = [&](size_t nelems) {
    float* p = ws + off;
    off += (nelems + 63) & ~(size_t)63;
    return p;
  };
  int* CNT = (int*)alloc(n);
  int* BSUM = (int*)alloc(256);
  int* BOFF = (int*)alloc(256);
  int* ROWP = (int*)alloc(n + 1);
  int* CURS = (int*)alloc(n);
  int* CSRS = (int*)alloc(nE);
  float* DINV = alloc(n);
  float* P = alloc((size_t)n * 256);   // GEMM outputs / xg / r1
  float* Hb = alloc((size_t)n * HD);   // hidden h
  float* HG = alloc((size_t)n * HD);   // aligned copy of hg
  float* ASD = alloc((size_t)n * NHEAD);
  float* ADD = alloc((size_t)n * NHEAD);
  float* GALPHA = alloc((size_t)nE * NHEAD);  // deg>128 fallback only
  float* GSUM = alloc(64);
  (void)ws_size;

  float* out = (float*)d_out;
  float* out_cls = out;                       // 2
  float* out_rec = out + 2;                   // n*256
  float* out_hg = out + 2 + (size_t)n * 256;  // n*64

  const int TB = 256;
  const int B = cdiv(n, TB);
  const int GM = cdiv(n, 64);  // GEMM M-tiles (782)

  // ---- CSR build (by dst, self-loops included) ----
  k_filli<<<cdiv(n, TB), TB, 0, stream>>>(CNT, 1, n);  // self loop
  k_count<<<cdiv(E, TB), TB, 0, stream>>>(dst, CNT, E);
  k_bsum<<<B, TB, 0, stream>>>(CNT, BSUM, n);
  k_bscan<<<1, TB, 0, stream>>>(BSUM, BOFF, B);
  k_rowptr<<<B, TB, 0, stream>>>(CNT, BOFF, ROWP, n, nE);
  k_copyi<<<cdiv(n, TB), TB, 0, stream>>>(ROWP, CURS, n);
  k_csrfill<<<cdiv(nE, TB), TB, 0, stream>>>(src, dst, CURS, CSRS, E, n);
  k_dinv<<<cdiv(n, TB), TB, 0, stream>>>(ROWP, DINV, n);

  // ---- GCN layers ----
  k_gemm2<256, 64, 0><<<dim3(GM, 1), TB, 0, stream>>>(x, W0, nullptr, P, n,
                                                      nullptr, nullptr, nullptr, nullptr);
  k_agg_csr<<<cdiv((long)n * 64, TB), TB, 0, stream>>>(P, CSRS, ROWP, DINV, b0, nullptr, Hb, n);

  k_gemm2<64, 64, 0><<<dim3(GM, 1), TB, 0, stream>>>(Hb, W1, nullptr, P, n,
                                                     nullptr, nullptr, nullptr, nullptr);
  k_agg_csr<<<cdiv((long)n * 64, TB), TB, 0, stream>>>(P, CSRS, ROWP, DINV, b1, Hb, Hb, n);

  k_gemm2<64, 64, 0><<<dim3(GM, 1), TB, 0, stream>>>(Hb, W2, nullptr, P, n,
                                                     nullptr, nullptr, nullptr, nullptr);
  k_agg_csr<<<cdiv((long)n * 64, TB), TB, 0, stream>>>(P, CSRS, ROWP, DINV, b2, Hb, Hb, n);

  // ---- GAT (att dots fused into GEMM epilogue) ----
  k_gemm2<64, 256, 3><<<dim3(GM, 4), TB, 0, stream>>>(Hb, Wg, nullptr, P, n,
                                                      att_src, att_dst, ASD, ADD);
  k_gat<<<cdiv((long)n * 64, TB), TB, 0, stream>>>(P, ASD, ADD, CSRS, ROWP, GALPHA, bg,
                                                   out_hg, HG, n);

  // ---- global pool + heads ----
  k_fill<<<1, TB, 0, stream>>>(GSUM, 0.f, 64);
  k_gsum<<<512, TB, 0, stream>>>(HG, GSUM, n);
  k_cls<<<1, 64, 0, stream>>>(GSUM, Wc1, bc1, Wc2, bc2, out_cls, n);
  k_gemm2<64, 64, 1><<<dim3(GM, 1), TB, 0, stream>>>(HG, Wr1, br1, P, n,
                                                     nullptr, nullptr, nullptr, nullptr);
  k_gemm2<64, 256, 2><<<dim3(GM, 4), TB, 0, stream>>>(P, Wr2, br2, out_rec, n,
                                                      nullptr, nullptr, nullptr, nullptr);
}

// Round 5
// 511.416 us; speedup vs baseline: 3.8397x; 1.0724x over previous
//
#include <hip/hip_runtime.h>

#define DIN 256
#define HD 64
#define NHEAD 4

static inline int cdiv(long a, long b) { return (int)((a + b - 1) / b); }

// ---------------- fills ----------------
__global__ __launch_bounds__(256) void k_fill(float* __restrict__ p, float v, int n) {
  int i = blockIdx.x * 256 + threadIdx.x;
  if (i < n) p[i] = v;
}
__global__ __launch_bounds__(256) void k_filli(int* __restrict__ p, int v, int n) {
  int i = blockIdx.x * 256 + threadIdx.x;
  if (i < n) p[i] = v;
}
__global__ __launch_bounds__(256) void k_copyi(const int* __restrict__ a, int* __restrict__ b, int n) {
  int i = blockIdx.x * 256 + threadIdx.x;
  if (i < n) b[i] = a[i];
}

// ---------------- CSR build ----------------
__global__ __launch_bounds__(256) void k_count(const int* __restrict__ dst,
                                               int* __restrict__ cnt, int E) {
  int i = blockIdx.x * 256 + threadIdx.x;
  if (i < E) atomicAdd(&cnt[dst[i]], 1);
}

__global__ __launch_bounds__(256) void k_bsum(const int* __restrict__ cnt,
                                              int* __restrict__ bsum, int n) {
  __shared__ int sd[256];
  int i = blockIdx.x * 256 + threadIdx.x;
  sd[threadIdx.x] = (i < n) ? cnt[i] : 0;
  __syncthreads();
  for (int o = 128; o > 0; o >>= 1) {
    if (threadIdx.x < o) sd[threadIdx.x] += sd[threadIdx.x + o];
    __syncthreads();
  }
  if (threadIdx.x == 0) bsum[blockIdx.x] = sd[0];
}

__global__ __launch_bounds__(256) void k_bscan(const int* __restrict__ bsum,
                                               int* __restrict__ boff, int B) {
  __shared__ int sd[256];
  int t = threadIdx.x;
  int v = (t < B) ? bsum[t] : 0;
  sd[t] = v;
  __syncthreads();
  for (int o = 1; o < 256; o <<= 1) {
    int x = (t >= o) ? sd[t - o] : 0;
    __syncthreads();
    sd[t] += x;
    __syncthreads();
  }
  if (t < B) boff[t] = sd[t] - v;  // exclusive
}

__global__ __launch_bounds__(256) void k_rowptr(const int* __restrict__ cnt,
                                                const int* __restrict__ boff,
                                                int* __restrict__ row_ptr, int n, int total) {
  __shared__ int sd[256];
  int t = threadIdx.x;
  int i = blockIdx.x * 256 + t;
  int v = (i < n) ? cnt[i] : 0;
  sd[t] = v;
  __syncthreads();
  for (int o = 1; o < 256; o <<= 1) {
    int x = (t >= o) ? sd[t - o] : 0;
    __syncthreads();
    sd[t] += x;
    __syncthreads();
  }
  if (i < n) row_ptr[i] = boff[blockIdx.x] + sd[t] - v;
  if (i == n - 1) row_ptr[n] = total;
}

__global__ __launch_bounds__(256) void k_csrfill(const int* __restrict__ src,
                                                 const int* __restrict__ dst,
                                                 int* __restrict__ cursor,
                                                 int* __restrict__ csr_src, int E, int n) {
  int e = blockIdx.x * 256 + threadIdx.x;
  if (e < E) {
    int pos = atomicAdd(&cursor[dst[e]], 1);
    csr_src[pos] = src[e];
  } else if (e < E + n) {
    int i = e - E;
    int pos = atomicAdd(&cursor[i], 1);
    csr_src[pos] = i;
  }
}

__global__ __launch_bounds__(256) void k_dinv(const int* __restrict__ row_ptr,
                                              float* __restrict__ dinv, int n) {
  int i = blockIdx.x * 256 + threadIdx.x;
  if (i < n) dinv[i] = rsqrtf((float)(row_ptr[i + 1] - row_ptr[i]));
}

// ---------------- bf16 helpers ----------------
__device__ __forceinline__ unsigned short f2bf(float f) {  // RNE
  unsigned u = __float_as_uint(f);
  u += 0x7FFFu + ((u >> 16) & 1u);
  return (unsigned short)(u >> 16);
}
__device__ __forceinline__ float bflo(unsigned u) { return __uint_as_float(u << 16); }
__device__ __forceinline__ float bfhi(unsigned u) { return __uint_as_float(u & 0xFFFF0000u); }

// ---------------- tiled GEMM: C[n,KOUT] = A[n,KIN] @ W[KIN,KOUT] ----------------
// 64x64 output tile per block, BK=64, 256 threads, 4x4 microtile per thread.
// MODE 0: plain  1: bias+relu  2: bias (float2 stores, C only 8B-aligned)
// MODE 3: bf16 xg store + fused att dots (a_s,a_d); no f32 C store
template <int KIN, int KOUT, int MODE>
__global__ __launch_bounds__(256, 4) void k_gemm2(const float* __restrict__ A,
                                                  const float* __restrict__ W,
                                                  const float* __restrict__ bias,
                                                  float* __restrict__ C, int n,
                                                  const float* __restrict__ attS,
                                                  const float* __restrict__ attD,
                                                  float* __restrict__ a_s,
                                                  float* __restrict__ a_d,
                                                  unsigned short* __restrict__ xg16) {
  constexpr int LD = 68;  // padded LDS stride (floats), keeps float4 alignment
  __shared__ float As[64][LD];
  __shared__ float Ws[64][LD];
  const int tid = threadIdx.x;
  const int tx = tid & 15;        // 0..15 -> output col group (4 cols)
  const int ty = tid >> 4;        // 0..15 -> output row base
  const int m0 = blockIdx.x * 64;
  const int n0 = blockIdx.y * 64;
  const int lr = tid >> 4;        // load row 0..15 (stride 16)
  const int lc = (tid & 15) * 4;  // load col (float4)
  float acc[4][4] = {};

  for (int k0 = 0; k0 < KIN; k0 += 64) {
#pragma unroll
    for (int q = 0; q < 4; ++q) {
      int r = lr + q * 16;
      int gr = m0 + r;
      gr = gr < n ? gr : n - 1;
      *(float4*)&As[r][lc] = *(const float4*)(A + (size_t)gr * KIN + k0 + lc);
      *(float4*)&Ws[r][lc] = *(const float4*)(W + (size_t)(k0 + r) * KOUT + n0 + lc);
    }
    __syncthreads();
#pragma unroll 2
    for (int k = 0; k < 64; k += 4) {
      float4 a0 = *(const float4*)&As[ty][k];
      float4 a1 = *(const float4*)&As[ty + 16][k];
      float4 a2 = *(const float4*)&As[ty + 32][k];
      float4 a3 = *(const float4*)&As[ty + 48][k];
      float4 w0 = *(const float4*)&Ws[k + 0][tx * 4];
      float4 w1 = *(const float4*)&Ws[k + 1][tx * 4];
      float4 w2 = *(const float4*)&Ws[k + 2][tx * 4];
      float4 w3 = *(const float4*)&Ws[k + 3][tx * 4];
#define FMA_ROW(i, av)                                                   \
      acc[i][0] = fmaf(av.x, w0.x, fmaf(av.y, w1.x, fmaf(av.z, w2.x, fmaf(av.w, w3.x, acc[i][0])))); \
      acc[i][1] = fmaf(av.x, w0.y, fmaf(av.y, w1.y, fmaf(av.z, w2.y, fmaf(av.w, w3.y, acc[i][1])))); \
      acc[i][2] = fmaf(av.x, w0.z, fmaf(av.y, w1.z, fmaf(av.z, w2.z, fmaf(av.w, w3.z, acc[i][2])))); \
      acc[i][3] = fmaf(av.x, w0.w, fmaf(av.y, w1.w, fmaf(av.z, w2.w, fmaf(av.w, w3.w, acc[i][3]))));
      FMA_ROW(0, a0)
      FMA_ROW(1, a1)
      FMA_ROW(2, a2)
      FMA_ROW(3, a3)
#undef FMA_ROW
    }
    __syncthreads();
  }

  float4 bv = {0.f, 0.f, 0.f, 0.f};
  if (MODE == 1 || MODE == 2) bv = *(const float4*)(bias + n0 + tx * 4);
  float4 attsv = {0.f, 0.f, 0.f, 0.f}, attdv = {0.f, 0.f, 0.f, 0.f};
  if (MODE == 3) {
    attsv = *(const float4*)(attS + blockIdx.y * 64 + tx * 4);
    attdv = *(const float4*)(attD + blockIdx.y * 64 + tx * 4);
  }
#pragma unroll
  for (int i = 0; i < 4; ++i) {
    int gr = m0 + ty + 16 * i;
    float4 r;
    r.x = acc[i][0]; r.y = acc[i][1]; r.z = acc[i][2]; r.w = acc[i][3];
    if (MODE == 1 || MODE == 2) {
      r.x += bv.x; r.y += bv.y; r.z += bv.z; r.w += bv.w;
      if (MODE == 1) {
        r.x = r.x > 0.f ? r.x : 0.f; r.y = r.y > 0.f ? r.y : 0.f;
        r.z = r.z > 0.f ? r.z : 0.f; r.w = r.w > 0.f ? r.w : 0.f;
      }
    }
    if (gr < n) {
      if (MODE == 2) {  // C only 8B-aligned (d_out + 2 floats)
        float2 lo; lo.x = r.x; lo.y = r.y;
        float2 hi; hi.x = r.z; hi.y = r.w;
        *(float2*)(C + (size_t)gr * KOUT + n0 + tx * 4) = lo;
        *(float2*)(C + (size_t)gr * KOUT + n0 + tx * 4 + 2) = hi;
      } else if (MODE != 3) {
        *(float4*)(C + (size_t)gr * KOUT + n0 + tx * 4) = r;
      }
    }
    if (MODE == 3) {
      if (gr < n) {
        uint2 pk;
        pk.x = (unsigned)f2bf(r.x) | ((unsigned)f2bf(r.y) << 16);
        pk.y = (unsigned)f2bf(r.z) | ((unsigned)f2bf(r.w) << 16);
        *(uint2*)(xg16 + (size_t)gr * 256 + n0 + tx * 4) = pk;
      }
      float pds = r.x * attsv.x + r.y * attsv.y + r.z * attsv.z + r.w * attsv.w;
      float pdd = r.x * attdv.x + r.y * attdv.y + r.z * attdv.z + r.w * attdv.w;
#pragma unroll
      for (int o = 8; o > 0; o >>= 1) {
        pds += __shfl_down(pds, o);
        pdd += __shfl_down(pdd, o);
      }
      if (tx == 0 && gr < n) {
        a_s[gr * NHEAD + blockIdx.y] = pds;
        a_d[gr * NHEAD + blockIdx.y] = pdd;
      }
    }
  }
}

// ---------------- GCN aggregation (CSR gather), 2-edge unroll ----------------
__global__ __launch_bounds__(256) void k_agg_csr(const float* __restrict__ P,
                                                 const int* __restrict__ csr_src,
                                                 const int* __restrict__ row_ptr,
                                                 const float* __restrict__ dinv,
                                                 const float* __restrict__ bias,
                                                 const float* __restrict__ resid,
                                                 float* __restrict__ out, int n) {
  int node = (blockIdx.x * 256 + threadIdx.x) >> 6;
  int lane = threadIdx.x & 63;
  if (node >= n) return;
  int beg = row_ptr[node], end = row_ptr[node + 1];
  float accA = 0.f, accB = 0.f;
  int i = beg;
  for (; i + 2 <= end; i += 2) {
    int s0 = csr_src[i], s1 = csr_src[i + 1];
    float d0 = dinv[s0], d1 = dinv[s1];
    float v0 = P[(size_t)s0 * HD + lane];
    float v1 = P[(size_t)s1 * HD + lane];
    accA = fmaf(v0, d0, accA);
    accB = fmaf(v1, d1, accB);
  }
  if (i < end) {
    int s = csr_src[i];
    accA = fmaf(P[(size_t)s * HD + lane], dinv[s], accA);
  }
  float v = (accA + accB) * dinv[node] + bias[lane];
  v = v > 0.f ? v : 0.f;
  if (resid) v += resid[(size_t)node * HD + lane];
  out[(size_t)node * HD + lane] = v;
}

// ---------------- GAT: fused segment softmax + bf16 gather ----------------
__device__ __forceinline__ float leaky(float v) { return v > 0.f ? v : 0.2f * v; }

__global__ __launch_bounds__(256) void k_gat(const unsigned short* __restrict__ xg16,
                                             const float* __restrict__ a_s,
                                             const float* __restrict__ a_d,
                                             const int* __restrict__ csr_src,
                                             const int* __restrict__ row_ptr,
                                             float* __restrict__ galpha,  // [nE][4] fallback
                                             const float* __restrict__ bg,
                                             float* __restrict__ hg,      // d_out slice (8B-aligned)
                                             float* __restrict__ hga,     // aligned ws copy
                                             int n) {
  __shared__ float4 ew[4][128];
  const int wid = threadIdx.x >> 6;
  const int node = (blockIdx.x * 256 + threadIdx.x) >> 6;
  const int lane = threadIdx.x & 63;
  if (node >= n) return;
  const int beg = row_ptr[node], end = row_ptr[node + 1];
  const bool uselds = (end - beg) <= 128;
  float4 ad = ((const float4*)a_d)[node];

  // P1: edge logits + lane-local max (no exp)
  float m0 = -1e30f, m1 = -1e30f, m2 = -1e30f, m3 = -1e30f;
  for (int i = beg + lane; i < end; i += 64) {
    int s = csr_src[i];
    float4 as = ((const float4*)a_s)[s];
    float4 e;
    e.x = leaky(as.x + ad.x); e.y = leaky(as.y + ad.y);
    e.z = leaky(as.z + ad.z); e.w = leaky(as.w + ad.w);
    if (uselds) ew[wid][i - beg] = e; else ((float4*)galpha)[i] = e;
    m0 = fmaxf(m0, e.x); m1 = fmaxf(m1, e.y);
    m2 = fmaxf(m2, e.z); m3 = fmaxf(m3, e.w);
  }
  if (!uselds) __threadfence();
#pragma unroll
  for (int o = 32; o > 0; o >>= 1) {
    m0 = fmaxf(m0, __shfl_xor(m0, o));
    m1 = fmaxf(m1, __shfl_xor(m1, o));
    m2 = fmaxf(m2, __shfl_xor(m2, o));
    m3 = fmaxf(m3, __shfl_xor(m3, o));
  }

  // P2: exp + lane-local sum
  float s0 = 0.f, s1 = 0.f, s2 = 0.f, s3 = 0.f;
  for (int i = beg + lane; i < end; i += 64) {
    float4 e = uselds ? ew[wid][i - beg] : ((const float4*)galpha)[i];
    float4 ex;
    ex.x = expf(e.x - m0); ex.y = expf(e.y - m1);
    ex.z = expf(e.z - m2); ex.w = expf(e.w - m3);
    if (uselds) ew[wid][i - beg] = ex; else ((float4*)galpha)[i] = ex;
    s0 += ex.x; s1 += ex.y; s2 += ex.z; s3 += ex.w;
  }
  if (!uselds) __threadfence();
#pragma unroll
  for (int o = 32; o > 0; o >>= 1) {
    s0 += __shfl_xor(s0, o);
    s1 += __shfl_xor(s1, o);
    s2 += __shfl_xor(s2, o);
    s3 += __shfl_xor(s3, o);
  }
  float r0 = 0.25f / s0, r1 = 0.25f / s1, r2 = 0.25f / s2, r3 = 0.25f / s3;

  // P3: bf16 gather. lane owns feats 4l..4l+3 of head l>>4 (one 8B load/edge).
  const int head = lane >> 4;
  const int fo = (lane & 15) * 4;
  float acc0 = 0.f, acc1 = 0.f, acc2 = 0.f, acc3 = 0.f;
  float bcc0 = 0.f, bcc1 = 0.f, bcc2 = 0.f, bcc3 = 0.f;
  int i = beg;
  for (; i + 2 <= end; i += 2) {
    int sA = csr_src[i], sB = csr_src[i + 1];
    float4 alA = uselds ? ew[wid][i - beg] : ((const float4*)galpha)[i];
    float4 alB = uselds ? ew[wid][i + 1 - beg] : ((const float4*)galpha)[i + 1];
    float aA = head == 0 ? alA.x : head == 1 ? alA.y : head == 2 ? alA.z : alA.w;
    float aB = head == 0 ? alB.x : head == 1 ? alB.y : head == 2 ? alB.z : alB.w;
    uint2 vA = *(const uint2*)(xg16 + (size_t)sA * 256 + lane * 4);
    uint2 vB = *(const uint2*)(xg16 + (size_t)sB * 256 + lane * 4);
    acc0 = fmaf(bflo(vA.x), aA, acc0);
    acc1 = fmaf(bfhi(vA.x), aA, acc1);
    acc2 = fmaf(bflo(vA.y), aA, acc2);
    acc3 = fmaf(bfhi(vA.y), aA, acc3);
    bcc0 = fmaf(bflo(vB.x), aB, bcc0);
    bcc1 = fmaf(bfhi(vB.x), aB, bcc1);
    bcc2 = fmaf(bflo(vB.y), aB, bcc2);
    bcc3 = fmaf(bfhi(vB.y), aB, bcc3);
  }
  if (i < end) {
    int s = csr_src[i];
    float4 al = uselds ? ew[wid][i - beg] : ((const float4*)galpha)[i];
    float a = head == 0 ? al.x : head == 1 ? al.y : head == 2 ? al.z : al.w;
    uint2 v = *(const uint2*)(xg16 + (size_t)s * 256 + lane * 4);
    acc0 = fmaf(bflo(v.x), a, acc0);
    acc1 = fmaf(bfhi(v.x), a, acc1);
    acc2 = fmaf(bflo(v.y), a, acc2);
    acc3 = fmaf(bfhi(v.y), a, acc3);
  }
  float rh = head == 0 ? r0 : head == 1 ? r1 : head == 2 ? r2 : r3;
  float t0 = (acc0 + bcc0) * rh, t1 = (acc1 + bcc1) * rh;
  float t2 = (acc2 + bcc2) * rh, t3 = (acc3 + bcc3) * rh;
  // combine heads: groups of 16 lanes hold heads 0..3 for the same feats
  t0 += __shfl_xor(t0, 16); t1 += __shfl_xor(t1, 16);
  t2 += __shfl_xor(t2, 16); t3 += __shfl_xor(t3, 16);
  t0 += __shfl_xor(t0, 32); t1 += __shfl_xor(t1, 32);
  t2 += __shfl_xor(t2, 32); t3 += __shfl_xor(t3, 32);
  if (lane < 16) {
    float4 o;
    o.x = t0 + bg[fo]; o.y = t1 + bg[fo + 1];
    o.z = t2 + bg[fo + 2]; o.w = t3 + bg[fo + 3];
    *(float4*)(hga + (size_t)node * HD + fo) = o;
    float2 lo; lo.x = o.x; lo.y = o.y;
    float2 hi; hi.x = o.z; hi.y = o.w;
    *(float2*)(hg + (size_t)node * HD + fo) = lo;
    *(float2*)(hg + (size_t)node * HD + fo + 2) = hi;
  }
}

// global feature sum of hg -> gsum[64]
__global__ __launch_bounds__(256) void k_gsum(const float* __restrict__ hg,
                                              float* __restrict__ gsum, int n) {
  __shared__ float red[256];
  int f = threadIdx.x & 63, g = threadIdx.x >> 6;
  float local = 0.f;
  for (int nd = blockIdx.x * 4 + g; nd < n; nd += gridDim.x * 4)
    local += hg[(size_t)nd * HD + f];
  red[threadIdx.x] = local;
  __syncthreads();
  if (threadIdx.x < 64)
    atomicAdd(&gsum[f], red[f] + red[64 + f] + red[128 + f] + red[192 + f]);
}

// tiny classifier head
__global__ __launch_bounds__(64) void k_cls(const float* __restrict__ gsum,
                                            const float* __restrict__ Wc1,
                                            const float* __restrict__ bc1,
                                            const float* __restrict__ Wc2,
                                            const float* __restrict__ bc2,
                                            float* __restrict__ out, int n) {
  __shared__ float hgl[64];
  __shared__ float t1[32];
  int t = threadIdx.x;
  hgl[t] = gsum[t] / (float)n;
  __syncthreads();
  if (t < 32) {
    float a = bc1[t];
#pragma unroll 16
    for (int f = 0; f < 64; ++f) a = fmaf(hgl[f], Wc1[f * 32 + t], a);
    t1[t] = a > 0.f ? a : 0.f;
  }
  __syncthreads();
  if (t < 2) {
    float a = bc2[t];
#pragma unroll
    for (int j = 0; j < 32; ++j) a = fmaf(t1[j], Wc2[j * 2 + t], a);
    out[t] = a;
  }
}

extern "C" void kernel_launch(void* const* d_in, const int* in_sizes, int n_in,
                              void* d_out, int out_size, void* d_ws, size_t ws_size,
                              hipStream_t stream) {
  const float* x = (const float*)d_in[0];
  const int* ei = (const int*)d_in[1];
  const float* W0 = (const float*)d_in[2];
  const float* b0 = (const float*)d_in[3];
  const float* W1 = (const float*)d_in[4];
  const float* b1 = (const float*)d_in[5];
  const float* W2 = (const float*)d_in[6];
  const float* b2 = (const float*)d_in[7];
  const float* Wg = (const float*)d_in[8];
  const float* att_src = (const float*)d_in[9];
  const float* att_dst = (const float*)d_in[10];
  const float* bg = (const float*)d_in[11];
  const float* Wc1 = (const float*)d_in[12];
  const float* bc1 = (const float*)d_in[13];
  const float* Wc2 = (const float*)d_in[14];
  const float* bc2 = (const float*)d_in[15];
  const float* Wr1 = (const float*)d_in[16];
  const float* br1 = (const float*)d_in[17];
  const float* Wr2 = (const float*)d_in[18];
  const float* br2 = (const float*)d_in[19];

  const int n = in_sizes[0] / DIN;  // 50000
  const int E = in_sizes[1] / 2;    // 800000
  const int nE = E + n;
  const int* src = ei;
  const int* dst = ei + E;

  // ---- workspace layout ----
  float* ws = (float*)d_ws;
  size_t off = 0;
  auto alloc = [&](size_t nelems) {
    float* p = ws + off;
    off += (nelems + 63) & ~(size_t)63;
    return p;
  };
  int* CNT = (int*)alloc(n);
  int* BSUM = (int*)alloc(256);
  int* BOFF = (int*)alloc(256);
  int* ROWP = (int*)alloc(n + 1);
  int* CURS = (int*)alloc(n);
  int* CSRS = (int*)alloc(nE);
  float* DINV = alloc(n);
  float* P = alloc((size_t)n * 256);             // GEMM outputs / r1
  unsigned short* XG16 = (unsigned short*)alloc((size_t)n * 128);  // bf16 xg
  float* Hb = alloc((size_t)n * HD);             // hidden h
  float* HG = alloc((size_t)n * HD);             // aligned copy of hg
  float* ASD = alloc((size_t)n * NHEAD);
  float* ADD = alloc((size_t)n * NHEAD);
  float* GALPHA = alloc((size_t)nE * NHEAD);     // deg>128 fallback only
  float* GSUM = alloc(64);
  (void)ws_size;

  float* out = (float*)d_out;
  float* out_cls = out;                       // 2
  float* out_rec = out + 2;                   // n*256
  float* out_hg = out + 2 + (size_t)n * 256;  // n*64

  const int TB = 256;
  const int B = cdiv(n, TB);
  const int GM = cdiv(n, 64);  // GEMM M-tiles (782)

  // ---- CSR build (by dst, self-loops included) ----
  k_filli<<<cdiv(n, TB), TB, 0, stream>>>(CNT, 1, n);  // self loop
  k_count<<<cdiv(E, TB), TB, 0, stream>>>(dst, CNT, E);
  k_bsum<<<B, TB, 0, stream>>>(CNT, BSUM, n);
  k_bscan<<<1, TB, 0, stream>>>(BSUM, BOFF, B);
  k_rowptr<<<B, TB, 0, stream>>>(CNT, BOFF, ROWP, n, nE);
  k_copyi<<<cdiv(n, TB), TB, 0, stream>>>(ROWP, CURS, n);
  k_csrfill<<<cdiv(nE, TB), TB, 0, stream>>>(src, dst, CURS, CSRS, E, n);
  k_dinv<<<cdiv(n, TB), TB, 0, stream>>>(ROWP, DINV, n);

  // ---- GCN layers ----
  k_gemm2<256, 64, 0><<<dim3(GM, 1), TB, 0, stream>>>(x, W0, nullptr, P, n,
                                                      nullptr, nullptr, nullptr, nullptr, nullptr);
  k_agg_csr<<<cdiv((long)n * 64, TB), TB, 0, stream>>>(P, CSRS, ROWP, DINV, b0, nullptr, Hb, n);

  k_gemm2<64, 64, 0><<<dim3(GM, 1), TB, 0, stream>>>(Hb, W1, nullptr, P, n,
                                                     nullptr, nullptr, nullptr, nullptr, nullptr);
  k_agg_csr<<<cdiv((long)n * 64, TB), TB, 0, stream>>>(P, CSRS, ROWP, DINV, b1, Hb, Hb, n);

  k_gemm2<64, 64, 0><<<dim3(GM, 1), TB, 0, stream>>>(Hb, W2, nullptr, P, n,
                                                     nullptr, nullptr, nullptr, nullptr, nullptr);
  k_agg_csr<<<cdiv((long)n * 64, TB), TB, 0, stream>>>(P, CSRS, ROWP, DINV, b2, Hb, Hb, n);

  // ---- GAT (bf16 xg + att dots fused into GEMM epilogue) ----
  k_gemm2<64, 256, 3><<<dim3(GM, 4), TB, 0, stream>>>(Hb, Wg, nullptr, nullptr, n,
                                                      att_src, att_dst, ASD, ADD, XG16);
  k_gat<<<cdiv((long)n * 64, TB), TB, 0, stream>>>(XG16, ASD, ADD, CSRS, ROWP, GALPHA, bg,
                                                   out_hg, HG, n);

  // ---- global pool + heads ----
  k_fill<<<1, TB, 0, stream>>>(GSUM, 0.f, 64);
  k_gsum<<<512, TB, 0, stream>>>(HG, GSUM, n);
  k_cls<<<1, 64, 0, stream>>>(GSUM, Wc1, bc1, Wc2, bc2, out_cls, n);
  k_gemm2<64, 64, 1><<<dim3(GM, 1), TB, 0, stream>>>(HG, Wr1, br1, P, n,
                                                     nullptr, nullptr, nullptr, nullptr, nullptr);
  k_gemm2<64, 256, 2><<<dim3(GM, 4), TB, 0, stream>>>(P, Wr2, br2, out_rec, n,
                                                      nullptr, nullptr, nullptr, nullptr, nullptr);
}

// Round 6
// 484.054 us; speedup vs baseline: 4.0568x; 1.0565x over previous
//
#include <hip/hip_runtime.h>

#define DIN 256
#define HD 64
#define NHEAD 4

static inline int cdiv(long a, long b) { return (int)((a + b - 1) / b); }

// ---------------- fills ----------------
__global__ __launch_bounds__(256) void k_fill(float* __restrict__ p, float v, int n) {
  int i = blockIdx.x * 256 + threadIdx.x;
  if (i < n) p[i] = v;
}
__global__ __launch_bounds__(256) void k_filli(int* __restrict__ p, int v, int n) {
  int i = blockIdx.x * 256 + threadIdx.x;
  if (i < n) p[i] = v;
}

// ---------------- CSR build ----------------
__global__ __launch_bounds__(256) void k_count(const int* __restrict__ dst,
                                               int* __restrict__ cnt, int E) {
  int i = blockIdx.x * 256 + threadIdx.x;
  if (i < E) atomicAdd(&cnt[dst[i]], 1);
}

__global__ __launch_bounds__(256) void k_bsum(const int* __restrict__ cnt,
                                              int* __restrict__ bsum, int n) {
  __shared__ int sd[256];
  int i = blockIdx.x * 256 + threadIdx.x;
  sd[threadIdx.x] = (i < n) ? cnt[i] : 0;
  __syncthreads();
  for (int o = 128; o > 0; o >>= 1) {
    if (threadIdx.x < o) sd[threadIdx.x] += sd[threadIdx.x + o];
    __syncthreads();
  }
  if (threadIdx.x == 0) bsum[blockIdx.x] = sd[0];
}

__global__ __launch_bounds__(256) void k_bscan(const int* __restrict__ bsum,
                                               int* __restrict__ boff, int B) {
  __shared__ int sd[256];
  int t = threadIdx.x;
  int v = (t < B) ? bsum[t] : 0;
  sd[t] = v;
  __syncthreads();
  for (int o = 1; o < 256; o <<= 1) {
    int x = (t >= o) ? sd[t - o] : 0;
    __syncthreads();
    sd[t] += x;
    __syncthreads();
  }
  if (t < B) boff[t] = sd[t] - v;  // exclusive
}

// rowptr + cursor init + dinv, fused
__global__ __launch_bounds__(256) void k_rowptr(const int* __restrict__ cnt,
                                                const int* __restrict__ boff,
                                                int* __restrict__ row_ptr,
                                                int* __restrict__ cursor,
                                                float* __restrict__ dinv, int n, int total) {
  __shared__ int sd[256];
  int t = threadIdx.x;
  int i = blockIdx.x * 256 + t;
  int v = (i < n) ? cnt[i] : 0;
  sd[t] = v;
  __syncthreads();
  for (int o = 1; o < 256; o <<= 1) {
    int x = (t >= o) ? sd[t - o] : 0;
    __syncthreads();
    sd[t] += x;
    __syncthreads();
  }
  if (i < n) {
    int rp = boff[blockIdx.x] + sd[t] - v;
    row_ptr[i] = rp;
    cursor[i] = rp;
    dinv[i] = rsqrtf((float)v);  // v = degree incl self-loop
  }
  if (i == n - 1) row_ptr[n] = total;
}

__global__ __launch_bounds__(256) void k_csrfill(const int* __restrict__ src,
                                                 const int* __restrict__ dst,
                                                 int* __restrict__ cursor,
                                                 int* __restrict__ csr_src, int E, int n) {
  int e = blockIdx.x * 256 + threadIdx.x;
  if (e < E) {
    int pos = atomicAdd(&cursor[dst[e]], 1);
    csr_src[pos] = src[e];
  } else if (e < E + n) {
    int i = e - E;
    int pos = atomicAdd(&cursor[i], 1);
    csr_src[pos] = i;
  }
}

// ---------------- bf16 helpers ----------------
__device__ __forceinline__ unsigned short f2bf(float f) {  // RNE
  unsigned u = __float_as_uint(f);
  u += 0x7FFFu + ((u >> 16) & 1u);
  return (unsigned short)(u >> 16);
}
__device__ __forceinline__ float bflo(unsigned u) { return __uint_as_float(u << 16); }
__device__ __forceinline__ float bfhi(unsigned u) { return __uint_as_float(u & 0xFFFF0000u); }

// ---------------- tiled GEMM: C[n,KOUT] = A[n,KIN] @ W[KIN,KOUT] ----------------
// 64x64 output tile per block, BK=64, 256 threads, 4x4 microtile per thread.
// MODE 0: plain f32  1: bias+relu  2: bias (float2 stores, 8B-aligned C)
// MODE 3: bf16 store + fused att dots  4: bf16 store only
template <int KIN, int KOUT, int MODE>
__global__ __launch_bounds__(256, 4) void k_gemm2(const float* __restrict__ A,
                                                  const float* __restrict__ W,
                                                  const float* __restrict__ bias,
                                                  float* __restrict__ C, int n,
                                                  const float* __restrict__ attS,
                                                  const float* __restrict__ attD,
                                                  float* __restrict__ a_s,
                                                  float* __restrict__ a_d,
                                                  unsigned short* __restrict__ c16) {
  constexpr int LD = 68;  // padded LDS stride (floats), keeps float4 alignment
  __shared__ float As[64][LD];
  __shared__ float Ws[64][LD];
  const int tid = threadIdx.x;
  const int tx = tid & 15;        // 0..15 -> output col group (4 cols)
  const int ty = tid >> 4;        // 0..15 -> output row base
  const int m0 = blockIdx.x * 64;
  const int n0 = blockIdx.y * 64;
  const int lr = tid >> 4;        // load row 0..15 (stride 16)
  const int lc = (tid & 15) * 4;  // load col (float4)
  float acc[4][4] = {};

  for (int k0 = 0; k0 < KIN; k0 += 64) {
#pragma unroll
    for (int q = 0; q < 4; ++q) {
      int r = lr + q * 16;
      int gr = m0 + r;
      gr = gr < n ? gr : n - 1;
      *(float4*)&As[r][lc] = *(const float4*)(A + (size_t)gr * KIN + k0 + lc);
      *(float4*)&Ws[r][lc] = *(const float4*)(W + (size_t)(k0 + r) * KOUT + n0 + lc);
    }
    __syncthreads();
#pragma unroll 2
    for (int k = 0; k < 64; k += 4) {
      float4 a0 = *(const float4*)&As[ty][k];
      float4 a1 = *(const float4*)&As[ty + 16][k];
      float4 a2 = *(const float4*)&As[ty + 32][k];
      float4 a3 = *(const float4*)&As[ty + 48][k];
      float4 w0 = *(const float4*)&Ws[k + 0][tx * 4];
      float4 w1 = *(const float4*)&Ws[k + 1][tx * 4];
      float4 w2 = *(const float4*)&Ws[k + 2][tx * 4];
      float4 w3 = *(const float4*)&Ws[k + 3][tx * 4];
#define FMA_ROW(i, av)                                                   \
      acc[i][0] = fmaf(av.x, w0.x, fmaf(av.y, w1.x, fmaf(av.z, w2.x, fmaf(av.w, w3.x, acc[i][0])))); \
      acc[i][1] = fmaf(av.x, w0.y, fmaf(av.y, w1.y, fmaf(av.z, w2.y, fmaf(av.w, w3.y, acc[i][1])))); \
      acc[i][2] = fmaf(av.x, w0.z, fmaf(av.y, w1.z, fmaf(av.z, w2.z, fmaf(av.w, w3.z, acc[i][2])))); \
      acc[i][3] = fmaf(av.x, w0.w, fmaf(av.y, w1.w, fmaf(av.z, w2.w, fmaf(av.w, w3.w, acc[i][3]))));
      FMA_ROW(0, a0)
      FMA_ROW(1, a1)
      FMA_ROW(2, a2)
      FMA_ROW(3, a3)
#undef FMA_ROW
    }
    __syncthreads();
  }

  float4 bv = {0.f, 0.f, 0.f, 0.f};
  if (MODE == 1 || MODE == 2) bv = *(const float4*)(bias + n0 + tx * 4);
  float4 attsv = {0.f, 0.f, 0.f, 0.f}, attdv = {0.f, 0.f, 0.f, 0.f};
  if (MODE == 3) {
    attsv = *(const float4*)(attS + blockIdx.y * 64 + tx * 4);
    attdv = *(const float4*)(attD + blockIdx.y * 64 + tx * 4);
  }
#pragma unroll
  for (int i = 0; i < 4; ++i) {
    int gr = m0 + ty + 16 * i;
    float4 r;
    r.x = acc[i][0]; r.y = acc[i][1]; r.z = acc[i][2]; r.w = acc[i][3];
    if (MODE == 1 || MODE == 2) {
      r.x += bv.x; r.y += bv.y; r.z += bv.z; r.w += bv.w;
      if (MODE == 1) {
        r.x = r.x > 0.f ? r.x : 0.f; r.y = r.y > 0.f ? r.y : 0.f;
        r.z = r.z > 0.f ? r.z : 0.f; r.w = r.w > 0.f ? r.w : 0.f;
      }
    }
    if (gr < n) {
      if (MODE == 2) {  // C only 8B-aligned (d_out + 2 floats)
        float2 lo; lo.x = r.x; lo.y = r.y;
        float2 hi; hi.x = r.z; hi.y = r.w;
        *(float2*)(C + (size_t)gr * KOUT + n0 + tx * 4) = lo;
        *(float2*)(C + (size_t)gr * KOUT + n0 + tx * 4 + 2) = hi;
      } else if (MODE == 3 || MODE == 4) {
        uint2 pk;
        pk.x = (unsigned)f2bf(r.x) | ((unsigned)f2bf(r.y) << 16);
        pk.y = (unsigned)f2bf(r.z) | ((unsigned)f2bf(r.w) << 16);
        *(uint2*)(c16 + (size_t)gr * KOUT + n0 + tx * 4) = pk;
      } else {
        *(float4*)(C + (size_t)gr * KOUT + n0 + tx * 4) = r;
      }
    }
    if (MODE == 3) {
      float pds = r.x * attsv.x + r.y * attsv.y + r.z * attsv.z + r.w * attsv.w;
      float pdd = r.x * attdv.x + r.y * attdv.y + r.z * attdv.z + r.w * attdv.w;
#pragma unroll
      for (int o = 8; o > 0; o >>= 1) {
        pds += __shfl_down(pds, o);
        pdd += __shfl_down(pdd, o);
      }
      if (tx == 0 && gr < n) {
        a_s[gr * NHEAD + blockIdx.y] = pds;
        a_d[gr * NHEAD + blockIdx.y] = pdd;
      }
    }
  }
}

// ---------------- GCN aggregation, bf16 gather ----------------
// wave per node; 2 edges/iter (half-waves), lane loads 1 uint = 2 bf16 feats.
__global__ __launch_bounds__(256) void k_agg16(const unsigned short* __restrict__ P16,
                                               const int* __restrict__ csr_src,
                                               const int* __restrict__ row_ptr,
                                               const float* __restrict__ dinv,
                                               const float* __restrict__ bias,
                                               const float* __restrict__ resid,
                                               float* __restrict__ out, int n) {
  int node = (blockIdx.x * 256 + threadIdx.x) >> 6;
  int lane = threadIdx.x & 63;
  if (node >= n) return;
  int beg = row_ptr[node], end = row_ptr[node + 1];
  int half = lane >> 5, hl = lane & 31;
  float acc0 = 0.f, acc1 = 0.f;
  int i = beg;
  for (; i + 2 <= end; i += 2) {
    int s = csr_src[i + half];  // uniform within half-wave
    float d = dinv[s];
    unsigned v = *(const unsigned*)(P16 + (size_t)s * HD + hl * 2);
    acc0 = fmaf(bflo(v), d, acc0);
    acc1 = fmaf(bfhi(v), d, acc1);
  }
  if (i < end && half == 0) {
    int s = csr_src[i];
    float d = dinv[s];
    unsigned v = *(const unsigned*)(P16 + (size_t)s * HD + hl * 2);
    acc0 = fmaf(bflo(v), d, acc0);
    acc1 = fmaf(bfhi(v), d, acc1);
  }
  acc0 += __shfl_xor(acc0, 32);
  acc1 += __shfl_xor(acc1, 32);
  if (lane < 32) {
    float dn = dinv[node];
    float v0 = acc0 * dn + bias[hl * 2];
    float v1 = acc1 * dn + bias[hl * 2 + 1];
    v0 = v0 > 0.f ? v0 : 0.f;
    v1 = v1 > 0.f ? v1 : 0.f;
    if (resid) {
      float2 rr = *(const float2*)(resid + (size_t)node * HD + hl * 2);
      v0 += rr.x; v1 += rr.y;
    }
    float2 o; o.x = v0; o.y = v1;
    *(float2*)(out + (size_t)node * HD + hl * 2) = o;
  }
}

// ---------------- GAT: fused segment softmax + bf16 gather ----------------
__device__ __forceinline__ float leaky(float v) { return v > 0.f ? v : 0.2f * v; }

__global__ __launch_bounds__(256) void k_gat(const unsigned short* __restrict__ xg16,
                                             const float* __restrict__ a_s,
                                             const float* __restrict__ a_d,
                                             const int* __restrict__ csr_src,
                                             const int* __restrict__ row_ptr,
                                             float* __restrict__ galpha,  // [nE][4] fallback
                                             const float* __restrict__ bg,
                                             float* __restrict__ hg,      // d_out slice (8B-aligned)
                                             float* __restrict__ hga,     // aligned ws copy
                                             int n) {
  __shared__ float4 ew[4][128];
  const int wid = threadIdx.x >> 6;
  const int node = (blockIdx.x * 256 + threadIdx.x) >> 6;
  const int lane = threadIdx.x & 63;
  if (node >= n) return;
  const int beg = row_ptr[node], end = row_ptr[node + 1];
  const bool uselds = (end - beg) <= 128;
  float4 ad = ((const float4*)a_d)[node];

  // P1: edge logits + lane-local max (no exp)
  float m0 = -1e30f, m1 = -1e30f, m2 = -1e30f, m3 = -1e30f;
  for (int i = beg + lane; i < end; i += 64) {
    int s = csr_src[i];
    float4 as = ((const float4*)a_s)[s];
    float4 e;
    e.x = leaky(as.x + ad.x); e.y = leaky(as.y + ad.y);
    e.z = leaky(as.z + ad.z); e.w = leaky(as.w + ad.w);
    if (uselds) ew[wid][i - beg] = e; else ((float4*)galpha)[i] = e;
    m0 = fmaxf(m0, e.x); m1 = fmaxf(m1, e.y);
    m2 = fmaxf(m2, e.z); m3 = fmaxf(m3, e.w);
  }
  if (!uselds) __threadfence();
#pragma unroll
  for (int o = 32; o > 0; o >>= 1) {
    m0 = fmaxf(m0, __shfl_xor(m0, o));
    m1 = fmaxf(m1, __shfl_xor(m1, o));
    m2 = fmaxf(m2, __shfl_xor(m2, o));
    m3 = fmaxf(m3, __shfl_xor(m3, o));
  }

  // P2: exp + lane-local sum
  float s0 = 0.f, s1 = 0.f, s2 = 0.f, s3 = 0.f;
  for (int i = beg + lane; i < end; i += 64) {
    float4 e = uselds ? ew[wid][i - beg] : ((const float4*)galpha)[i];
    float4 ex;
    ex.x = expf(e.x - m0); ex.y = expf(e.y - m1);
    ex.z = expf(e.z - m2); ex.w = expf(e.w - m3);
    if (uselds) ew[wid][i - beg] = ex; else ((float4*)galpha)[i] = ex;
    s0 += ex.x; s1 += ex.y; s2 += ex.z; s3 += ex.w;
  }
  if (!uselds) __threadfence();
#pragma unroll
  for (int o = 32; o > 0; o >>= 1) {
    s0 += __shfl_xor(s0, o);
    s1 += __shfl_xor(s1, o);
    s2 += __shfl_xor(s2, o);
    s3 += __shfl_xor(s3, o);
  }
  float r0 = 0.25f / s0, r1 = 0.25f / s1, r2 = 0.25f / s2, r3 = 0.25f / s3;

  // P3: bf16 gather. lane owns feats 4l..4l+3 of head l>>4 (one 8B load/edge).
  const int head = lane >> 4;
  const int fo = (lane & 15) * 4;
  float acc0 = 0.f, acc1 = 0.f, acc2 = 0.f, acc3 = 0.f;
  float bcc0 = 0.f, bcc1 = 0.f, bcc2 = 0.f, bcc3 = 0.f;
  int i = beg;
  for (; i + 2 <= end; i += 2) {
    int sA = csr_src[i], sB = csr_src[i + 1];
    float4 alA = uselds ? ew[wid][i - beg] : ((const float4*)galpha)[i];
    float4 alB = uselds ? ew[wid][i + 1 - beg] : ((const float4*)galpha)[i + 1];
    float aA = head == 0 ? alA.x : head == 1 ? alA.y : head == 2 ? alA.z : alA.w;
    float aB = head == 0 ? alB.x : head == 1 ? alB.y : head == 2 ? alB.z : alB.w;
    uint2 vA = *(const uint2*)(xg16 + (size_t)sA * 256 + lane * 4);
    uint2 vB = *(const uint2*)(xg16 + (size_t)sB * 256 + lane * 4);
    acc0 = fmaf(bflo(vA.x), aA, acc0);
    acc1 = fmaf(bfhi(vA.x), aA, acc1);
    acc2 = fmaf(bflo(vA.y), aA, acc2);
    acc3 = fmaf(bfhi(vA.y), aA, acc3);
    bcc0 = fmaf(bflo(vB.x), aB, bcc0);
    bcc1 = fmaf(bfhi(vB.x), aB, bcc1);
    bcc2 = fmaf(bflo(vB.y), aB, bcc2);
    bcc3 = fmaf(bfhi(vB.y), aB, bcc3);
  }
  if (i < end) {
    int s = csr_src[i];
    float4 al = uselds ? ew[wid][i - beg] : ((const float4*)galpha)[i];
    float a = head == 0 ? al.x : head == 1 ? al.y : head == 2 ? al.z : al.w;
    uint2 v = *(const uint2*)(xg16 + (size_t)s * 256 + lane * 4);
    acc0 = fmaf(bflo(v.x), a, acc0);
    acc1 = fmaf(bfhi(v.x), a, acc1);
    acc2 = fmaf(bflo(v.y), a, acc2);
    acc3 = fmaf(bfhi(v.y), a, acc3);
  }
  float rh = head == 0 ? r0 : head == 1 ? r1 : head == 2 ? r2 : r3;
  float t0 = (acc0 + bcc0) * rh, t1 = (acc1 + bcc1) * rh;
  float t2 = (acc2 + bcc2) * rh, t3 = (acc3 + bcc3) * rh;
  // combine heads: groups of 16 lanes hold heads 0..3 for the same feats
  t0 += __shfl_xor(t0, 16); t1 += __shfl_xor(t1, 16);
  t2 += __shfl_xor(t2, 16); t3 += __shfl_xor(t3, 16);
  t0 += __shfl_xor(t0, 32); t1 += __shfl_xor(t1, 32);
  t2 += __shfl_xor(t2, 32); t3 += __shfl_xor(t3, 32);
  if (lane < 16) {
    float4 o;
    o.x = t0 + bg[fo]; o.y = t1 + bg[fo + 1];
    o.z = t2 + bg[fo + 2]; o.w = t3 + bg[fo + 3];
    *(float4*)(hga + (size_t)node * HD + fo) = o;
    float2 lo; lo.x = o.x; lo.y = o.y;
    float2 hi; hi.x = o.z; hi.y = o.w;
    *(float2*)(hg + (size_t)node * HD + fo) = lo;
    *(float2*)(hg + (size_t)node * HD + fo + 2) = hi;
  }
}

// global feature sum of hg -> gsum[64]
__global__ __launch_bounds__(256) void k_gsum(const float* __restrict__ hg,
                                              float* __restrict__ gsum, int n) {
  __shared__ float red[256];
  int f = threadIdx.x & 63, g = threadIdx.x >> 6;
  float local = 0.f;
  for (int nd = blockIdx.x * 4 + g; nd < n; nd += gridDim.x * 4)
    local += hg[(size_t)nd * HD + f];
  red[threadIdx.x] = local;
  __syncthreads();
  if (threadIdx.x < 64)
    atomicAdd(&gsum[f], red[f] + red[64 + f] + red[128 + f] + red[192 + f]);
}

// tiny classifier head
__global__ __launch_bounds__(64) void k_cls(const float* __restrict__ gsum,
                                            const float* __restrict__ Wc1,
                                            const float* __restrict__ bc1,
                                            const float* __restrict__ Wc2,
                                            const float* __restrict__ bc2,
                                            float* __restrict__ out, int n) {
  __shared__ float hgl[64];
  __shared__ float t1[32];
  int t = threadIdx.x;
  hgl[t] = gsum[t] / (float)n;
  __syncthreads();
  if (t < 32) {
    float a = bc1[t];
#pragma unroll 16
    for (int f = 0; f < 64; ++f) a = fmaf(hgl[f], Wc1[f * 32 + t], a);
    t1[t] = a > 0.f ? a : 0.f;
  }
  __syncthreads();
  if (t < 2) {
    float a = bc2[t];
#pragma unroll
    for (int j = 0; j < 32; ++j) a = fmaf(t1[j], Wc2[j * 2 + t], a);
    out[t] = a;
  }
}

extern "C" void kernel_launch(void* const* d_in, const int* in_sizes, int n_in,
                              void* d_out, int out_size, void* d_ws, size_t ws_size,
                              hipStream_t stream) {
  const float* x = (const float*)d_in[0];
  const int* ei = (const int*)d_in[1];
  const float* W0 = (const float*)d_in[2];
  const float* b0 = (const float*)d_in[3];
  const float* W1 = (const float*)d_in[4];
  const float* b1 = (const float*)d_in[5];
  const float* W2 = (const float*)d_in[6];
  const float* b2 = (const float*)d_in[7];
  const float* Wg = (const float*)d_in[8];
  const float* att_src = (const float*)d_in[9];
  const float* att_dst = (const float*)d_in[10];
  const float* bg = (const float*)d_in[11];
  const float* Wc1 = (const float*)d_in[12];
  const float* bc1 = (const float*)d_in[13];
  const float* Wc2 = (const float*)d_in[14];
  const float* bc2 = (const float*)d_in[15];
  const float* Wr1 = (const float*)d_in[16];
  const float* br1 = (const float*)d_in[17];
  const float* Wr2 = (const float*)d_in[18];
  const float* br2 = (const float*)d_in[19];

  const int n = in_sizes[0] / DIN;  // 50000
  const int E = in_sizes[1] / 2;    // 800000
  const int nE = E + n;
  const int* src = ei;
  const int* dst = ei + E;

  // ---- workspace layout ----
  float* ws = (float*)d_ws;
  size_t off = 0;
  auto alloc = [&](size_t nelems) {
    float* p = ws + off;
    off += (nelems + 63) & ~(size_t)63;
    return p;
  };
  int* CNT = (int*)alloc(n);
  int* BSUM = (int*)alloc(256);
  int* BOFF = (int*)alloc(256);
  int* ROWP = (int*)alloc(n + 1);
  int* CURS = (int*)alloc(n);
  int* CSRS = (int*)alloc(nE);
  float* DINV = alloc(n);
  float* P = alloc((size_t)n * 256);                               // f32 scratch (r1)
  unsigned short* XG16 = (unsigned short*)alloc((size_t)n * 128);  // bf16 xg [n,256]
  unsigned short* P16 = (unsigned short*)alloc((size_t)n * 32);    // bf16 P [n,64]
  float* Hb = alloc((size_t)n * HD);                               // hidden h
  float* HG = alloc((size_t)n * HD);                               // aligned copy of hg
  float* ASD = alloc((size_t)n * NHEAD);
  float* ADD = alloc((size_t)n * NHEAD);
  float* GALPHA = alloc((size_t)nE * NHEAD);  // deg>128 fallback only
  float* GSUM = alloc(64);
  (void)ws_size;

  float* out = (float*)d_out;
  float* out_cls = out;                       // 2
  float* out_rec = out + 2;                   // n*256
  float* out_hg = out + 2 + (size_t)n * 256;  // n*64

  const int TB = 256;
  const int B = cdiv(n, TB);
  const int GM = cdiv(n, 64);  // GEMM M-tiles (782)

  // ---- CSR build (by dst, self-loops included) ----
  k_filli<<<cdiv(n, TB), TB, 0, stream>>>(CNT, 1, n);  // self loop
  k_count<<<cdiv(E, TB), TB, 0, stream>>>(dst, CNT, E);
  k_bsum<<<B, TB, 0, stream>>>(CNT, BSUM, n);
  k_bscan<<<1, TB, 0, stream>>>(BSUM, BOFF, B);
  k_rowptr<<<B, TB, 0, stream>>>(CNT, BOFF, ROWP, CURS, DINV, n, nE);
  k_csrfill<<<cdiv(nE, TB), TB, 0, stream>>>(src, dst, CURS, CSRS, E, n);

  // ---- GCN layers (bf16 message gather) ----
  k_gemm2<256, 64, 4><<<dim3(GM, 1), TB, 0, stream>>>(x, W0, nullptr, nullptr, n,
                                                      nullptr, nullptr, nullptr, nullptr, P16);
  k_agg16<<<cdiv((long)n * 64, TB), TB, 0, stream>>>(P16, CSRS, ROWP, DINV, b0, nullptr, Hb, n);

  k_gemm2<64, 64, 4><<<dim3(GM, 1), TB, 0, stream>>>(Hb, W1, nullptr, nullptr, n,
                                                     nullptr, nullptr, nullptr, nullptr, P16);
  k_agg16<<<cdiv((long)n * 64, TB), TB, 0, stream>>>(P16, CSRS, ROWP, DINV, b1, Hb, Hb, n);

  k_gemm2<64, 64, 4><<<dim3(GM, 1), TB, 0, stream>>>(Hb, W2, nullptr, nullptr, n,
                                                     nullptr, nullptr, nullptr, nullptr, P16);
  k_agg16<<<cdiv((long)n * 64, TB), TB, 0, stream>>>(P16, CSRS, ROWP, DINV, b2, Hb, Hb, n);

  // ---- GAT (bf16 xg + att dots fused into GEMM epilogue) ----
  k_gemm2<64, 256, 3><<<dim3(GM, 4), TB, 0, stream>>>(Hb, Wg, nullptr, nullptr, n,
                                                      att_src, att_dst, ASD, ADD, XG16);
  k_gat<<<cdiv((long)n * 64, TB), TB, 0, stream>>>(XG16, ASD, ADD, CSRS, ROWP, GALPHA, bg,
                                                   out_hg, HG, n);

  // ---- global pool + heads ----
  k_fill<<<1, TB, 0, stream>>>(GSUM, 0.f, 64);
  k_gsum<<<512, TB, 0, stream>>>(HG, GSUM, n);
  k_cls<<<1, 64, 0, stream>>>(GSUM, Wc1, bc1, Wc2, bc2, out_cls, n);
  k_gemm2<64, 64, 1><<<dim3(GM, 1), TB, 0, stream>>>(HG, Wr1, br1, P, n,
                                                     nullptr, nullptr, nullptr, nullptr, nullptr);
  k_gemm2<64, 256, 2><<<dim3(GM, 4), TB, 0, stream>>>(P, Wr2, br2, out_rec, n,
                                                      nullptr, nullptr, nullptr, nullptr, nullptr);
}

// Round 7
// 455.523 us; speedup vs baseline: 4.3109x; 1.0626x over previous
//
#include <hip/hip_runtime.h>

#define DIN 256
#define HD 64
#define NHEAD 4

static inline int cdiv(long a, long b) { return (int)((a + b - 1) / b); }

typedef __attribute__((ext_vector_type(8))) short bf16x8;
typedef __attribute__((ext_vector_type(4))) float f32x4;

// ---------------- fills ----------------
__global__ __launch_bounds__(256) void k_fill(float* __restrict__ p, float v, int n) {
  int i = blockIdx.x * 256 + threadIdx.x;
  if (i < n) p[i] = v;
}
__global__ __launch_bounds__(256) void k_filli(int* __restrict__ p, int v, int n) {
  int i = blockIdx.x * 256 + threadIdx.x;
  if (i < n) p[i] = v;
}

// ---------------- CSR build ----------------
__global__ __launch_bounds__(256) void k_count(const int* __restrict__ dst,
                                               int* __restrict__ cnt, int E) {
  int i = blockIdx.x * 256 + threadIdx.x;
  if (i < E) atomicAdd(&cnt[dst[i]], 1);
}

__global__ __launch_bounds__(256) void k_bsum(const int* __restrict__ cnt,
                                              int* __restrict__ bsum, int n) {
  __shared__ int sd[256];
  int i = blockIdx.x * 256 + threadIdx.x;
  sd[threadIdx.x] = (i < n) ? cnt[i] : 0;
  __syncthreads();
  for (int o = 128; o > 0; o >>= 1) {
    if (threadIdx.x < o) sd[threadIdx.x] += sd[threadIdx.x + o];
    __syncthreads();
  }
  if (threadIdx.x == 0) bsum[blockIdx.x] = sd[0];
}

__global__ __launch_bounds__(256) void k_bscan(const int* __restrict__ bsum,
                                               int* __restrict__ boff, int B) {
  __shared__ int sd[256];
  int t = threadIdx.x;
  int v = (t < B) ? bsum[t] : 0;
  sd[t] = v;
  __syncthreads();
  for (int o = 1; o < 256; o <<= 1) {
    int x = (t >= o) ? sd[t - o] : 0;
    __syncthreads();
    sd[t] += x;
    __syncthreads();
  }
  if (t < B) boff[t] = sd[t] - v;  // exclusive
}

// rowptr + cursor init + dinv, fused
__global__ __launch_bounds__(256) void k_rowptr(const int* __restrict__ cnt,
                                                const int* __restrict__ boff,
                                                int* __restrict__ row_ptr,
                                                int* __restrict__ cursor,
                                                float* __restrict__ dinv, int n, int total) {
  __shared__ int sd[256];
  int t = threadIdx.x;
  int i = blockIdx.x * 256 + t;
  int v = (i < n) ? cnt[i] : 0;
  sd[t] = v;
  __syncthreads();
  for (int o = 1; o < 256; o <<= 1) {
    int x = (t >= o) ? sd[t - o] : 0;
    __syncthreads();
    sd[t] += x;
    __syncthreads();
  }
  if (i < n) {
    int rp = boff[blockIdx.x] + sd[t] - v;
    row_ptr[i] = rp;
    cursor[i] = rp;
    dinv[i] = rsqrtf((float)v);  // v = degree incl self-loop
  }
  if (i == n - 1) row_ptr[n] = total;
}

__global__ __launch_bounds__(256) void k_csrfill(const int* __restrict__ src,
                                                 const int* __restrict__ dst,
                                                 int* __restrict__ cursor,
                                                 int* __restrict__ csr_src, int E, int n) {
  int e = blockIdx.x * 256 + threadIdx.x;
  if (e < E) {
    int pos = atomicAdd(&cursor[dst[e]], 1);
    csr_src[pos] = src[e];
  } else if (e < E + n) {
    int i = e - E;
    int pos = atomicAdd(&cursor[i], 1);
    csr_src[pos] = i;
  }
}

// ---------------- bf16 helpers ----------------
__device__ __forceinline__ unsigned short f2bf(float f) {  // RNE
  unsigned u = __float_as_uint(f);
  u += 0x7FFFu + ((u >> 16) & 1u);
  return (unsigned short)(u >> 16);
}
__device__ __forceinline__ float bflo(unsigned u) { return __uint_as_float(u << 16); }
__device__ __forceinline__ float bfhi(unsigned u) { return __uint_as_float(u & 0xFFFF0000u); }

// ---------------- MFMA GEMM: c16[n,KOUT](bf16) = A[n,KIN](f32) @ W[KIN,KOUT](f32) ----------------
// 64x64 tile per block, 4 waves; per wave: 16 rows x 64 cols (4 MFMA n-subtiles).
// A and W^T staged in LDS as bf16 with granule XOR swizzle (8-elt granules).
template <int KIN, int KOUT>
__global__ __launch_bounds__(256, 4) void k_gmfma(const float* __restrict__ A,
                                                  const float* __restrict__ W,
                                                  unsigned short* __restrict__ c16, int n) {
  __shared__ unsigned short As[64][64];  // [row][k, granule-swizzled]
  __shared__ unsigned short Wt[64][64];  // [col][k, granule-swizzled]
  const int tid = threadIdx.x;
  const int m0 = blockIdx.x * 64;
  const int n0 = blockIdx.y * 64;
  const int lane = tid & 63;
  const int wid = tid >> 6;
  const int wm = wid * 16;       // wave row base
  const int fr = lane & 15;      // frag row (A) / col (B) / col (D)
  const int fg = lane >> 4;      // k-granule sub-index 0..3
  f32x4 acc[4] = {{0.f, 0.f, 0.f, 0.f},
                  {0.f, 0.f, 0.f, 0.f},
                  {0.f, 0.f, 0.f, 0.f},
                  {0.f, 0.f, 0.f, 0.f}};

  for (int k0 = 0; k0 < KIN; k0 += 64) {
    // ---- stage A tile (f32 -> bf16, swizzled) ----
    {
      int row = tid >> 3;  // 0..31
      int g = tid & 7;
#pragma unroll
      for (int q = 0; q < 2; ++q, row += 32) {
        int gr = m0 + row;
        gr = gr < n ? gr : n - 1;
        const float* ap = A + (size_t)gr * KIN + k0 + g * 8;
        float4 f0 = *(const float4*)ap;
        float4 f1 = *(const float4*)(ap + 4);
        uint4 pk;
        pk.x = (unsigned)f2bf(f0.x) | ((unsigned)f2bf(f0.y) << 16);
        pk.y = (unsigned)f2bf(f0.z) | ((unsigned)f2bf(f0.w) << 16);
        pk.z = (unsigned)f2bf(f1.x) | ((unsigned)f2bf(f1.y) << 16);
        pk.w = (unsigned)f2bf(f1.z) | ((unsigned)f2bf(f1.w) << 16);
        *(uint4*)&As[row][(g ^ (row & 7)) * 8] = pk;
      }
    }
    // ---- stage W^T tile (f32 -> bf16, transpose, swizzled) ----
    {
      int col = tid & 63;
      int kb = (tid >> 6) * 16;  // 0,16,32,48
      unsigned pk[8];
#pragma unroll
      for (int i = 0; i < 8; ++i) {
        float lo = W[(size_t)(k0 + kb + 2 * i) * KOUT + n0 + col];
        float hi = W[(size_t)(k0 + kb + 2 * i + 1) * KOUT + n0 + col];
        pk[i] = (unsigned)f2bf(lo) | ((unsigned)f2bf(hi) << 16);
      }
      int g0 = kb >> 3;
      uint4 w0; w0.x = pk[0]; w0.y = pk[1]; w0.z = pk[2]; w0.w = pk[3];
      uint4 w1; w1.x = pk[4]; w1.y = pk[5]; w1.z = pk[6]; w1.w = pk[7];
      *(uint4*)&Wt[col][((g0) ^ (col & 7)) * 8] = w0;
      *(uint4*)&Wt[col][((g0 + 1) ^ (col & 7)) * 8] = w1;
    }
    __syncthreads();
    // ---- MFMA: 2 k-steps of 32 ----
#pragma unroll
    for (int ks = 0; ks < 2; ++ks) {
      int ga = ks * 4 + fg;
      bf16x8 af = *(const bf16x8*)&As[wm + fr][(ga ^ (fr & 7)) * 8];
#pragma unroll
      for (int nt = 0; nt < 4; ++nt) {
        bf16x8 bfr = *(const bf16x8*)&Wt[nt * 16 + fr][(ga ^ (fr & 7)) * 8];
        acc[nt] = __builtin_amdgcn_mfma_f32_16x16x32_bf16(af, bfr, acc[nt], 0, 0, 0);
      }
    }
    __syncthreads();
  }

  // ---- epilogue: bf16 store. D: row=(lane>>4)*4+r, col=lane&15 ----
#pragma unroll
  for (int nt = 0; nt < 4; ++nt) {
#pragma unroll
    for (int r = 0; r < 4; ++r) {
      int row = m0 + wm + fg * 4 + r;
      if (row < n) {
        c16[(size_t)row * KOUT + n0 + nt * 16 + fr] = f2bf(acc[nt][r]);
      }
    }
  }
}

// ---------------- att dots from bf16 xg: a_s[n,4], a_d[n,4] ----------------
__global__ __launch_bounds__(256) void k_att16(const unsigned short* __restrict__ xg16,
                                               const float* __restrict__ attS,
                                               const float* __restrict__ attD,
                                               float* __restrict__ a_s,
                                               float* __restrict__ a_d, int n) {
  int node = (blockIdx.x * 256 + threadIdx.x) >> 6;
  int lane = threadIdx.x & 63;
  if (node >= n) return;
  int h = lane >> 4, f4 = (lane & 15) * 4;
  uint2 v = *(const uint2*)(xg16 + (size_t)node * 256 + h * 64 + f4);
  float4 s = *(const float4*)(attS + h * 64 + f4);
  float4 d = *(const float4*)(attD + h * 64 + f4);
  float ps = bflo(v.x) * s.x + bfhi(v.x) * s.y + bflo(v.y) * s.z + bfhi(v.y) * s.w;
  float pd = bflo(v.x) * d.x + bfhi(v.x) * d.y + bflo(v.y) * d.z + bfhi(v.y) * d.w;
#pragma unroll
  for (int o = 8; o > 0; o >>= 1) {
    ps += __shfl_xor(ps, o);
    pd += __shfl_xor(pd, o);
  }
  if ((lane & 15) == 0) {
    a_s[node * NHEAD + h] = ps;
    a_d[node * NHEAD + h] = pd;
  }
}

// ---------------- tiled vector GEMM (f32): C[n,KOUT] = A[n,KIN] @ W[KIN,KOUT] ----------------
// MODE 1: bias+relu (f32 C)   MODE 2: bias (float2 stores, 8B-aligned C)
template <int KIN, int KOUT, int MODE>
__global__ __launch_bounds__(256, 4) void k_gemm2(const float* __restrict__ A,
                                                  const float* __restrict__ W,
                                                  const float* __restrict__ bias,
                                                  float* __restrict__ C, int n) {
  constexpr int LD = 68;
  __shared__ float As[64][LD];
  __shared__ float Ws[64][LD];
  const int tid = threadIdx.x;
  const int tx = tid & 15;
  const int ty = tid >> 4;
  const int m0 = blockIdx.x * 64;
  const int n0 = blockIdx.y * 64;
  const int lr = tid >> 4;
  const int lc = (tid & 15) * 4;
  float acc[4][4] = {};

  for (int k0 = 0; k0 < KIN; k0 += 64) {
#pragma unroll
    for (int q = 0; q < 4; ++q) {
      int r = lr + q * 16;
      int gr = m0 + r;
      gr = gr < n ? gr : n - 1;
      *(float4*)&As[r][lc] = *(const float4*)(A + (size_t)gr * KIN + k0 + lc);
      *(float4*)&Ws[r][lc] = *(const float4*)(W + (size_t)(k0 + r) * KOUT + n0 + lc);
    }
    __syncthreads();
#pragma unroll 2
    for (int k = 0; k < 64; k += 4) {
      float4 a0 = *(const float4*)&As[ty][k];
      float4 a1 = *(const float4*)&As[ty + 16][k];
      float4 a2 = *(const float4*)&As[ty + 32][k];
      float4 a3 = *(const float4*)&As[ty + 48][k];
      float4 w0 = *(const float4*)&Ws[k + 0][tx * 4];
      float4 w1 = *(const float4*)&Ws[k + 1][tx * 4];
      float4 w2 = *(const float4*)&Ws[k + 2][tx * 4];
      float4 w3 = *(const float4*)&Ws[k + 3][tx * 4];
#define FMA_ROW(i, av)                                                   \
      acc[i][0] = fmaf(av.x, w0.x, fmaf(av.y, w1.x, fmaf(av.z, w2.x, fmaf(av.w, w3.x, acc[i][0])))); \
      acc[i][1] = fmaf(av.x, w0.y, fmaf(av.y, w1.y, fmaf(av.z, w2.y, fmaf(av.w, w3.y, acc[i][1])))); \
      acc[i][2] = fmaf(av.x, w0.z, fmaf(av.y, w1.z, fmaf(av.z, w2.z, fmaf(av.w, w3.z, acc[i][2])))); \
      acc[i][3] = fmaf(av.x, w0.w, fmaf(av.y, w1.w, fmaf(av.z, w2.w, fmaf(av.w, w3.w, acc[i][3]))));
      FMA_ROW(0, a0)
      FMA_ROW(1, a1)
      FMA_ROW(2, a2)
      FMA_ROW(3, a3)
#undef FMA_ROW
    }
    __syncthreads();
  }

  float4 bv = *(const float4*)(bias + n0 + tx * 4);
#pragma unroll
  for (int i = 0; i < 4; ++i) {
    int gr = m0 + ty + 16 * i;
    float4 r;
    r.x = acc[i][0] + bv.x; r.y = acc[i][1] + bv.y;
    r.z = acc[i][2] + bv.z; r.w = acc[i][3] + bv.w;
    if (MODE == 1) {
      r.x = r.x > 0.f ? r.x : 0.f; r.y = r.y > 0.f ? r.y : 0.f;
      r.z = r.z > 0.f ? r.z : 0.f; r.w = r.w > 0.f ? r.w : 0.f;
    }
    if (gr < n) {
      if (MODE == 2) {  // C only 8B-aligned (d_out + 2 floats)
        float2 lo; lo.x = r.x; lo.y = r.y;
        float2 hi; hi.x = r.z; hi.y = r.w;
        *(float2*)(C + (size_t)gr * KOUT + n0 + tx * 4) = lo;
        *(float2*)(C + (size_t)gr * KOUT + n0 + tx * 4 + 2) = hi;
      } else {
        *(float4*)(C + (size_t)gr * KOUT + n0 + tx * 4) = r;
      }
    }
  }
}

// ---------------- GCN aggregation, bf16 gather ----------------
__global__ __launch_bounds__(256) void k_agg16(const unsigned short* __restrict__ P16,
                                               const int* __restrict__ csr_src,
                                               const int* __restrict__ row_ptr,
                                               const float* __restrict__ dinv,
                                               const float* __restrict__ bias,
                                               const float* __restrict__ resid,
                                               float* __restrict__ out, int n) {
  int node = (blockIdx.x * 256 + threadIdx.x) >> 6;
  int lane = threadIdx.x & 63;
  if (node >= n) return;
  int beg = row_ptr[node], end = row_ptr[node + 1];
  int half = lane >> 5, hl = lane & 31;
  float acc0 = 0.f, acc1 = 0.f;
  int i = beg;
  for (; i + 2 <= end; i += 2) {
    int s = csr_src[i + half];  // uniform within half-wave
    float d = dinv[s];
    unsigned v = *(const unsigned*)(P16 + (size_t)s * HD + hl * 2);
    acc0 = fmaf(bflo(v), d, acc0);
    acc1 = fmaf(bfhi(v), d, acc1);
  }
  if (i < end && half == 0) {
    int s = csr_src[i];
    float d = dinv[s];
    unsigned v = *(const unsigned*)(P16 + (size_t)s * HD + hl * 2);
    acc0 = fmaf(bflo(v), d, acc0);
    acc1 = fmaf(bfhi(v), d, acc1);
  }
  acc0 += __shfl_xor(acc0, 32);
  acc1 += __shfl_xor(acc1, 32);
  if (lane < 32) {
    float dn = dinv[node];
    float v0 = acc0 * dn + bias[hl * 2];
    float v1 = acc1 * dn + bias[hl * 2 + 1];
    v0 = v0 > 0.f ? v0 : 0.f;
    v1 = v1 > 0.f ? v1 : 0.f;
    if (resid) {
      float2 rr = *(const float2*)(resid + (size_t)node * HD + hl * 2);
      v0 += rr.x; v1 += rr.y;
    }
    float2 o; o.x = v0; o.y = v1;
    *(float2*)(out + (size_t)node * HD + hl * 2) = o;
  }
}

// ---------------- GAT: fused segment softmax + bf16 gather ----------------
__device__ __forceinline__ float leaky(float v) { return v > 0.f ? v : 0.2f * v; }

__global__ __launch_bounds__(256) void k_gat(const unsigned short* __restrict__ xg16,
                                             const float* __restrict__ a_s,
                                             const float* __restrict__ a_d,
                                             const int* __restrict__ csr_src,
                                             const int* __restrict__ row_ptr,
                                             float* __restrict__ galpha,  // [nE][4] fallback
                                             const float* __restrict__ bg,
                                             float* __restrict__ hg,      // d_out slice (8B-aligned)
                                             float* __restrict__ hga,     // aligned ws copy
                                             int n) {
  __shared__ float4 ew[4][128];
  const int wid = threadIdx.x >> 6;
  const int node = (blockIdx.x * 256 + threadIdx.x) >> 6;
  const int lane = threadIdx.x & 63;
  if (node >= n) return;
  const int beg = row_ptr[node], end = row_ptr[node + 1];
  const bool uselds = (end - beg) <= 128;
  float4 ad = ((const float4*)a_d)[node];

  // P1: edge logits + lane-local max (no exp)
  float m0 = -1e30f, m1 = -1e30f, m2 = -1e30f, m3 = -1e30f;
  for (int i = beg + lane; i < end; i += 64) {
    int s = csr_src[i];
    float4 as = ((const float4*)a_s)[s];
    float4 e;
    e.x = leaky(as.x + ad.x); e.y = leaky(as.y + ad.y);
    e.z = leaky(as.z + ad.z); e.w = leaky(as.w + ad.w);
    if (uselds) ew[wid][i - beg] = e; else ((float4*)galpha)[i] = e;
    m0 = fmaxf(m0, e.x); m1 = fmaxf(m1, e.y);
    m2 = fmaxf(m2, e.z); m3 = fmaxf(m3, e.w);
  }
  if (!uselds) __threadfence();
#pragma unroll
  for (int o = 32; o > 0; o >>= 1) {
    m0 = fmaxf(m0, __shfl_xor(m0, o));
    m1 = fmaxf(m1, __shfl_xor(m1, o));
    m2 = fmaxf(m2, __shfl_xor(m2, o));
    m3 = fmaxf(m3, __shfl_xor(m3, o));
  }

  // P2: exp + lane-local sum
  float s0 = 0.f, s1 = 0.f, s2 = 0.f, s3 = 0.f;
  for (int i = beg + lane; i < end; i += 64) {
    float4 e = uselds ? ew[wid][i - beg] : ((const float4*)galpha)[i];
    float4 ex;
    ex.x = expf(e.x - m0); ex.y = expf(e.y - m1);
    ex.z = expf(e.z - m2); ex.w = expf(e.w - m3);
    if (uselds) ew[wid][i - beg] = ex; else ((float4*)galpha)[i] = ex;
    s0 += ex.x; s1 += ex.y; s2 += ex.z; s3 += ex.w;
  }
  if (!uselds) __threadfence();
#pragma unroll
  for (int o = 32; o > 0; o >>= 1) {
    s0 += __shfl_xor(s0, o);
    s1 += __shfl_xor(s1, o);
    s2 += __shfl_xor(s2, o);
    s3 += __shfl_xor(s3, o);
  }
  float r0 = 0.25f / s0, r1 = 0.25f / s1, r2 = 0.25f / s2, r3 = 0.25f / s3;

  // P3: bf16 gather. lane owns feats 4l..4l+3 of head l>>4 (one 8B load/edge).
  const int head = lane >> 4;
  const int fo = (lane & 15) * 4;
  float acc0 = 0.f, acc1 = 0.f, acc2 = 0.f, acc3 = 0.f;
  float bcc0 = 0.f, bcc1 = 0.f, bcc2 = 0.f, bcc3 = 0.f;
  int i = beg;
  for (; i + 2 <= end; i += 2) {
    int sA = csr_src[i], sB = csr_src[i + 1];
    float4 alA = uselds ? ew[wid][i - beg] : ((const float4*)galpha)[i];
    float4 alB = uselds ? ew[wid][i + 1 - beg] : ((const float4*)galpha)[i + 1];
    float aA = head == 0 ? alA.x : head == 1 ? alA.y : head == 2 ? alA.z : alA.w;
    float aB = head == 0 ? alB.x : head == 1 ? alB.y : head == 2 ? alB.z : alB.w;
    uint2 vA = *(const uint2*)(xg16 + (size_t)sA * 256 + lane * 4);
    uint2 vB = *(const uint2*)(xg16 + (size_t)sB * 256 + lane * 4);
    acc0 = fmaf(bflo(vA.x), aA, acc0);
    acc1 = fmaf(bfhi(vA.x), aA, acc1);
    acc2 = fmaf(bflo(vA.y), aA, acc2);
    acc3 = fmaf(bfhi(vA.y), aA, acc3);
    bcc0 = fmaf(bflo(vB.x), aB, bcc0);
    bcc1 = fmaf(bfhi(vB.x), aB, bcc1);
    bcc2 = fmaf(bflo(vB.y), aB, bcc2);
    bcc3 = fmaf(bfhi(vB.y), aB, bcc3);
  }
  if (i < end) {
    int s = csr_src[i];
    float4 al = uselds ? ew[wid][i - beg] : ((const float4*)galpha)[i];
    float a = head == 0 ? al.x : head == 1 ? al.y : head == 2 ? al.z : al.w;
    uint2 v = *(const uint2*)(xg16 + (size_t)s * 256 + lane * 4);
    acc0 = fmaf(bflo(v.x), a, acc0);
    acc1 = fmaf(bfhi(v.x), a, acc1);
    acc2 = fmaf(bflo(v.y), a, acc2);
    acc3 = fmaf(bfhi(v.y), a, acc3);
  }
  float rh = head == 0 ? r0 : head == 1 ? r1 : head == 2 ? r2 : r3;
  float t0 = (acc0 + bcc0) * rh, t1 = (acc1 + bcc1) * rh;
  float t2 = (acc2 + bcc2) * rh, t3 = (acc3 + bcc3) * rh;
  // combine heads: groups of 16 lanes hold heads 0..3 for the same feats
  t0 += __shfl_xor(t0, 16); t1 += __shfl_xor(t1, 16);
  t2 += __shfl_xor(t2, 16); t3 += __shfl_xor(t3, 16);
  t0 += __shfl_xor(t0, 32); t1 += __shfl_xor(t1, 32);
  t2 += __shfl_xor(t2, 32); t3 += __shfl_xor(t3, 32);
  if (lane < 16) {
    float4 o;
    o.x = t0 + bg[fo]; o.y = t1 + bg[fo + 1];
    o.z = t2 + bg[fo + 2]; o.w = t3 + bg[fo + 3];
    *(float4*)(hga + (size_t)node * HD + fo) = o;
    float2 lo; lo.x = o.x; lo.y = o.y;
    float2 hi; hi.x = o.z; hi.y = o.w;
    *(float2*)(hg + (size_t)node * HD + fo) = lo;
    *(float2*)(hg + (size_t)node * HD + fo + 2) = hi;
  }
}

// global feature sum of hg -> gsum[64]
__global__ __launch_bounds__(256) void k_gsum(const float* __restrict__ hg,
                                              float* __restrict__ gsum, int n) {
  __shared__ float red[256];
  int f = threadIdx.x & 63, g = threadIdx.x >> 6;
  float local = 0.f;
  for (int nd = blockIdx.x * 4 + g; nd < n; nd += gridDim.x * 4)
    local += hg[(size_t)nd * HD + f];
  red[threadIdx.x] = local;
  __syncthreads();
  if (threadIdx.x < 64)
    atomicAdd(&gsum[f], red[f] + red[64 + f] + red[128 + f] + red[192 + f]);
}

// tiny classifier head
__global__ __launch_bounds__(64) void k_cls(const float* __restrict__ gsum,
                                            const float* __restrict__ Wc1,
                                            const float* __restrict__ bc1,
                                            const float* __restrict__ Wc2,
                                            const float* __restrict__ bc2,
                                            float* __restrict__ out, int n) {
  __shared__ float hgl[64];
  __shared__ float t1[32];
  int t = threadIdx.x;
  hgl[t] = gsum[t] / (float)n;
  __syncthreads();
  if (t < 32) {
    float a = bc1[t];
#pragma unroll 16
    for (int f = 0; f < 64; ++f) a = fmaf(hgl[f], Wc1[f * 32 + t], a);
    t1[t] = a > 0.f ? a : 0.f;
  }
  __syncthreads();
  if (t < 2) {
    float a = bc2[t];
#pragma unroll
    for (int j = 0; j < 32; ++j) a = fmaf(t1[j], Wc2[j * 2 + t], a);
    out[t] = a;
  }
}

extern "C" void kernel_launch(void* const* d_in, const int* in_sizes, int n_in,
                              void* d_out, int out_size, void* d_ws, size_t ws_size,
                              hipStream_t stream) {
  const float* x = (const float*)d_in[0];
  const int* ei = (const int*)d_in[1];
  const float* W0 = (const float*)d_in[2];
  const float* b0 = (const float*)d_in[3];
  const float* W1 = (const float*)d_in[4];
  const float* b1 = (const float*)d_in[5];
  const float* W2 = (const float*)d_in[6];
  const float* b2 = (const float*)d_in[7];
  const float* Wg = (const float*)d_in[8];
  const float* att_src = (const float*)d_in[9];
  const float* att_dst = (const float*)d_in[10];
  const float* bg = (const float*)d_in[11];
  const float* Wc1 = (const float*)d_in[12];
  const float* bc1 = (const float*)d_in[13];
  const float* Wc2 = (const float*)d_in[14];
  const float* bc2 = (const float*)d_in[15];
  const float* Wr1 = (const float*)d_in[16];
  const float* br1 = (const float*)d_in[17];
  const float* Wr2 = (const float*)d_in[18];
  const float* br2 = (const float*)d_in[19];

  const int n = in_sizes[0] / DIN;  // 50000
  const int E = in_sizes[1] / 2;    // 800000
  const int nE = E + n;
  const int* src = ei;
  const int* dst = ei + E;

  // ---- workspace layout ----
  float* ws = (float*)d_ws;
  size_t off = 0;
  auto alloc = [&](size_t nelems) {
    float* p = ws + off;
    off += (nelems + 63) & ~(size_t)63;
    return p;
  };
  int* CNT = (int*)alloc(n);
  int* BSUM = (int*)alloc(256);
  int* BOFF = (int*)alloc(256);
  int* ROWP = (int*)alloc(n + 1);
  int* CURS = (int*)alloc(n);
  int* CSRS = (int*)alloc(nE);
  float* DINV = alloc(n);
  float* P = alloc((size_t)n * 256);                               // f32 scratch (r1)
  unsigned short* XG16 = (unsigned short*)alloc((size_t)n * 128);  // bf16 xg [n,256]
  unsigned short* P16 = (unsigned short*)alloc((size_t)n * 32);    // bf16 P [n,64]
  float* Hb = alloc((size_t)n * HD);                               // hidden h
  float* HG = alloc((size_t)n * HD);                               // aligned copy of hg
  float* ASD = alloc((size_t)n * NHEAD);
  float* ADD = alloc((size_t)n * NHEAD);
  float* GALPHA = alloc((size_t)nE * NHEAD);  // deg>128 fallback only
  float* GSUM = alloc(64);
  (void)ws_size;

  float* out = (float*)d_out;
  float* out_cls = out;                       // 2
  float* out_rec = out + 2;                   // n*256
  float* out_hg = out + 2 + (size_t)n * 256;  // n*64

  const int TB = 256;
  const int B = cdiv(n, TB);
  const int GM = cdiv(n, 64);  // GEMM M-tiles (782)

  // ---- CSR build (by dst, self-loops included) ----
  k_filli<<<cdiv(n, TB), TB, 0, stream>>>(CNT, 1, n);  // self loop
  k_count<<<cdiv(E, TB), TB, 0, stream>>>(dst, CNT, E);
  k_bsum<<<B, TB, 0, stream>>>(CNT, BSUM, n);
  k_bscan<<<1, TB, 0, stream>>>(BSUM, BOFF, B);
  k_rowptr<<<B, TB, 0, stream>>>(CNT, BOFF, ROWP, CURS, DINV, n, nE);
  k_csrfill<<<cdiv(nE, TB), TB, 0, stream>>>(src, dst, CURS, CSRS, E, n);

  // ---- GCN layers (MFMA GEMM -> bf16 message gather) ----
  k_gmfma<256, 64><<<dim3(GM, 1), TB, 0, stream>>>(x, W0, P16, n);
  k_agg16<<<cdiv((long)n * 64, TB), TB, 0, stream>>>(P16, CSRS, ROWP, DINV, b0, nullptr, Hb, n);

  k_gmfma<64, 64><<<dim3(GM, 1), TB, 0, stream>>>(Hb, W1, P16, n);
  k_agg16<<<cdiv((long)n * 64, TB), TB, 0, stream>>>(P16, CSRS, ROWP, DINV, b1, Hb, Hb, n);

  k_gmfma<64, 64><<<dim3(GM, 1), TB, 0, stream>>>(Hb, W2, P16, n);
  k_agg16<<<cdiv((long)n * 64, TB), TB, 0, stream>>>(P16, CSRS, ROWP, DINV, b2, Hb, Hb, n);

  // ---- GAT ----
  k_gmfma<64, 256><<<dim3(GM, 4), TB, 0, stream>>>(Hb, Wg, XG16, n);
  k_att16<<<cdiv((long)n * 64, TB), TB, 0, stream>>>(XG16, att_src, att_dst, ASD, ADD, n);
  k_gat<<<cdiv((long)n * 64, TB), TB, 0, stream>>>(XG16, ASD, ADD, CSRS, ROWP, GALPHA, bg,
                                                   out_hg, HG, n);

  // ---- global pool + heads (f32 vector GEMMs for precision) ----
  k_fill<<<1, TB, 0, stream>>>(GSUM, 0.f, 64);
  k_gsum<<<512, TB, 0, stream>>>(HG, GSUM, n);
  k_cls<<<1, 64, 0, stream>>>(GSUM, Wc1, bc1, Wc2, bc2, out_cls, n);
  k_gemm2<64, 64, 1><<<dim3(GM, 1), TB, 0, stream>>>(HG, Wr1, br1, P, n);
  k_gemm2<64, 256, 2><<<dim3(GM, 4), TB, 0, stream>>>(P, Wr2, br2, out_rec, n);
}